// Round 6
// baseline (497.520 us; speedup 1.0000x reference)
//
#include <hip/hip_runtime.h>

typedef unsigned short u16;
typedef unsigned int u32;
typedef __bf16 bf16_t;
typedef bf16_t bf16x8 __attribute__((ext_vector_type(8)));
typedef float f32x4 __attribute__((ext_vector_type(4)));
typedef float f32x2 __attribute__((ext_vector_type(2)));

#define N_NODES 30000
#define N_EDGES 480000

static __device__ __forceinline__ float b2f(u16 u) {
  return __uint_as_float(((u32)u) << 16);
}
static __device__ __forceinline__ float b2f_lo(u32 w) {
  return __uint_as_float(w << 16);
}
static __device__ __forceinline__ float b2f_hi(u32 w) {
  return __uint_as_float(w & 0xffff0000u);
}
static __device__ __forceinline__ u16 f2b(float f) {
  u32 x = __float_as_uint(f);
  u32 r = (x + 0x7fffu + ((x >> 16) & 1u)) >> 16;
  return (u16)r;
}

// ---------------- init: zero deg; block 0 sniffs dtype (bf16=0 / f32=1) ----------------
__global__ __launch_bounds__(256) void init_sniff_deg(const u16* __restrict__ h,
                                                      int* __restrict__ flag,
                                                      int* __restrict__ deg) {
  int i = blockIdx.x * 256 + threadIdx.x;
  if (i < N_NODES) deg[i] = 0;
  if (blockIdx.x == 0) {
    int t = threadIdx.x;
    int bad = 0;
#pragma unroll
    for (int j = 0; j < 4; j++) {
      u32 e = ((u32)h[t * 4 + j] >> 7) & 0xFFu;
      if (e >= 0x8Eu) bad = 1;  // impossible magnitude for N(0,1) bf16 data
    }
    int r = __syncthreads_or(bad);
    if (t == 0) *flag = r ? 1 : 0;
  }
}

struct ConvDesc { const void* s; u16* d; int n; int off; };
struct ConvTab { ConvDesc e[20]; int total; };

// ---------------- fused front-end: deg_count | conv h | conv ef | conv params ----------------
__global__ __launch_bounds__(256) void conv_all(
    const int* __restrict__ dstE, int* __restrict__ deg,
    const void* __restrict__ hsrc, u16* __restrict__ c_h,
    const void* __restrict__ efsrc, u16* __restrict__ c_ef,
    ConvTab tab, const int* __restrict__ flag) {
  int b = blockIdx.x;
  const int t = threadIdx.x;
  if (b < 1875) {
    int e = b * 256 + t;
    if (e < N_EDGES) atomicAdd(&deg[dstE[e]], 1);
    return;
  }
  b -= 1875;
  const int f = *flag;
  if (b < 3750) {  // h: 960000 uint2-groups
    int i = b * 256 + t;
    if (f) {
      float4 v = ((const float4*)hsrc)[i];
      uint2 o;
      o.x = (u32)f2b(v.x) | ((u32)f2b(v.y) << 16);
      o.y = (u32)f2b(v.z) | ((u32)f2b(v.w) << 16);
      ((uint2*)c_h)[i] = o;
    } else {
      ((uint2*)c_h)[i] = ((const uint2*)hsrc)[i];
    }
    return;
  }
  b -= 3750;
  if (b < 2813) {  // ef: 720000 4-elem groups
    int i = b * 256 + t;
    if (i < 720000) {
      if (f) {
        float4 v = ((const float4*)efsrc)[i];
        uint2 o;
        o.x = (u32)f2b(v.x) | ((u32)f2b(v.y) << 16);
        o.y = (u32)f2b(v.z) | ((u32)f2b(v.w) << 16);
        ((uint2*)c_ef)[i] = o;
      } else {
        ((uint2*)c_ef)[i] = ((const uint2*)efsrc)[i];
      }
    }
    return;
  }
  b -= 2813;
  int i = b * 256 + t;
  if (i >= tab.total) return;
#pragma unroll 1
  for (int a = 0; a < 20; a++) {
    int j = i - tab.e[a].off;
    if (j >= 0 && j < tab.e[a].n) {
      if (f) tab.e[a].d[j] = f2b(((const float*)tab.e[a].s)[j]);
      else tab.e[a].d[j] = ((const u16*)tab.e[a].s)[j];
      return;
    }
  }
}

// ---------------- single-block scan, thread-serial chunks (exact int math) ----------------
__global__ __launch_bounds__(1024) void scan_off(const int* __restrict__ deg,
                                                 int* __restrict__ off,
                                                 int* __restrict__ cursor, int n) {
  __shared__ int wsum[16];
  const int t = threadIdx.x, lane = t & 63, wv = t >> 6;
  const int CH = 30;  // 1024*30 = 30720 >= 30000
  int base = t * CH;
  int v[CH];
  int s = 0;
#pragma unroll
  for (int j = 0; j < CH; j++) {
    int idx = base + j;
    int d = (idx < n) ? deg[idx] : 0;
    v[j] = s;  // exclusive within chunk
    s += d;
  }
  int x = s;
#pragma unroll
  for (int d = 1; d < 64; d <<= 1) {
    int y = __shfl_up(x, d, 64);
    if (lane >= d) x += y;
  }
  if (lane == 63) wsum[wv] = x;
  __syncthreads();
  int wadd = 0;
  for (int w = 0; w < wv; w++) wadd += wsum[w];
  int pref = (x - s) + wadd;  // exclusive prefix of this thread's chunk
  if (t == 0) off[0] = 0;
#pragma unroll
  for (int j = 0; j < CH; j++) {
    int idx = base + j;
    if (idx < n) {
      int excl = pref + v[j];
      int incl = pref + ((j + 1 < CH) ? v[j + 1] : s);
      cursor[idx] = excl;
      off[idx + 1] = incl;
    }
  }
}

// ---------------- weight prep body (block-id offset already applied) ----------------
static __device__ void prep_body(
    int b, int t,
    const u16* __restrict__ encWp, const u16* __restrict__ encWs, const u16* __restrict__ encWn,
    const u16* __restrict__ decWp, const u16* __restrict__ decWs, const u16* __restrict__ decWn,
    const u16* __restrict__ epW1, const u16* __restrict__ epb1,
    u16* __restrict__ wt_encpool, u16* __restrict__ wt_enc,
    u16* __restrict__ wt_decpool, u16* __restrict__ wt_dec,
    u16* __restrict__ wt_UV, u16* __restrict__ b512, float* __restrict__ swsum) {
  if (b < 64) {
    int idx = b * 256 + t; int k = idx >> 7, n = idx & 127;
    wt_encpool[n * 128 + k] = encWp[k * 128 + n]; return;
  }
  b -= 64;
  if (b < 128) {
    int idx = b * 256 + t; int k = idx >> 8, n = idx & 255;
    wt_enc[n * 256 + k] = encWs[k * 256 + n]; return;
  }
  b -= 128;
  if (b < 128) {
    int idx = b * 256 + t; int k = idx >> 8, n = idx & 255;
    wt_enc[n * 256 + 128 + k] = encWn[k * 256 + n]; return;
  }
  b -= 128;
  if (b < 256) {
    int idx = b * 256 + t; int k = idx >> 8, n = idx & 255;
    wt_decpool[n * 256 + k] = decWp[k * 256 + n]; return;
  }
  b -= 256;
  if (b < 128) {
    int idx = b * 256 + t; int k = idx >> 7, n = idx & 127;
    wt_dec[n * 512 + k] = decWs[k * 128 + n]; return;
  }
  b -= 128;
  if (b < 128) {
    int idx = b * 256 + t; int k = idx >> 7, n = idx & 127;
    wt_dec[n * 512 + 256 + k] = decWn[k * 128 + n]; return;
  }
  b -= 128;
  if (b < 512) {
    int n = b, n2 = n & 255, base = (n >= 256) ? 267 : 0;
    for (int kp = t; kp < 288; kp += 256) {
      u16 v = (kp < 261) ? epW1[(size_t)(base + kp) * 256 + n2] : (u16)0;
      wt_UV[(size_t)n * 288 + kp] = v;
    }
    return;
  }
  b -= 512;
  if (b < 2) {
    int i = b * 256 + t;
    b512[i] = (i < 256) ? epb1[i] : (u16)0; return;
  }
  int k = t >> 5, l32 = t & 31;
  if (k < 6) {
    uint4 v = *(const uint4*)(epW1 + (size_t)(261 + k) * 256 + l32 * 8);
    float s = b2f_lo(v.x) + b2f_hi(v.x) + b2f_lo(v.y) + b2f_hi(v.y) +
              b2f_lo(v.z) + b2f_hi(v.z) + b2f_lo(v.w) + b2f_hi(v.w);
#pragma unroll
    for (int m = 1; m < 32; m <<= 1) s += __shfl_xor(s, m, 64);
    if (l32 == 0) swsum[k] = s;
  }
}

// ---------------- MERGED: fill_csr (1875) + prep_weights (1347) ----------------
__global__ __launch_bounds__(256) void fill_prep(
    const int* __restrict__ src, const int* __restrict__ dst,
    int* __restrict__ cursor, int* __restrict__ esrc,
    const u16* __restrict__ encWp, const u16* __restrict__ encWs, const u16* __restrict__ encWn,
    const u16* __restrict__ decWp, const u16* __restrict__ decWs, const u16* __restrict__ decWn,
    const u16* __restrict__ epW1, const u16* __restrict__ epb1,
    u16* __restrict__ wt_encpool, u16* __restrict__ wt_enc,
    u16* __restrict__ wt_decpool, u16* __restrict__ wt_dec,
    u16* __restrict__ wt_UV, u16* __restrict__ b512, float* __restrict__ swsum) {
  int b = blockIdx.x;
  if (b < 1875) {
    int e = b * 256 + threadIdx.x;
    if (e < N_EDGES) {
      int p = atomicAdd(&cursor[dst[e]], 1);
      esrc[p] = src[e];
    }
    return;
  }
  prep_body(b - 1875, threadIdx.x, encWp, encWs, encWn, decWp, decWs, decWn,
            epW1, epb1, wt_encpool, wt_enc, wt_decpool, wt_dec, wt_UV, b512, swsum);
}

#define MRG(r)                                                    \
  do {                                                            \
    a0 = max(a0, (r).x & 0xffffu); a1 = max(a1, (r).x >> 16);     \
    a2 = max(a2, (r).y & 0xffffu); a3 = max(a3, (r).y >> 16);     \
    a4 = max(a4, (r).z & 0xffffu); a5 = max(a5, (r).z >> 16);     \
    a6 = max(a6, (r).w & 0xffffu); a7 = max(a7, (r).w >> 16);     \
  } while (0)

// ---------------- CSR max-aggregate (unsigned max == float max for bf16 >= 0) ----------------
// 4 nodes per wave; 16 lanes x uint4 per row (128 cols).
__global__ __launch_bounds__(256) void agg128(const u16* __restrict__ m,
                                              const int* __restrict__ esrc,
                                              const int* __restrict__ off,
                                              u16* __restrict__ out) {
  int wv = threadIdx.x >> 6, lane = threadIdx.x & 63;
  int qd = lane >> 4, l = lane & 15;
  int n = blockIdx.x * 16 + wv * 4 + qd;
  if (n >= N_NODES) return;
  int i = off[n], s1 = off[n + 1];
  u32 a0 = 0, a1 = 0, a2 = 0, a3 = 0, a4 = 0, a5 = 0, a6 = 0, a7 = 0;
  for (; i + 1 < s1; i += 2) {
    int e0 = esrc[i], e1 = esrc[i + 1];
    uint4 r0 = *(const uint4*)(m + (size_t)e0 * 128 + l * 8);
    uint4 r1 = *(const uint4*)(m + (size_t)e1 * 128 + l * 8);
    MRG(r0); MRG(r1);
  }
  if (i < s1) {
    uint4 r0 = *(const uint4*)(m + (size_t)esrc[i] * 128 + l * 8);
    MRG(r0);
  }
  uint4 w;
  w.x = a0 | (a1 << 16); w.y = a2 | (a3 << 16);
  w.z = a4 | (a5 << 16); w.w = a6 | (a7 << 16);
  *(uint4*)(out + (size_t)n * 128 + l * 8) = w;
}

// 2 nodes per wave; 32 lanes x uint4 per row (256 cols).
__global__ __launch_bounds__(256) void agg256(const u16* __restrict__ m,
                                              const int* __restrict__ esrc,
                                              const int* __restrict__ off,
                                              u16* __restrict__ out) {
  int wv = threadIdx.x >> 6, lane = threadIdx.x & 63;
  int half = lane >> 5, l = lane & 31;
  int n = blockIdx.x * 8 + wv * 2 + half;
  if (n >= N_NODES) return;
  int i = off[n], s1 = off[n + 1];
  u32 a0 = 0, a1 = 0, a2 = 0, a3 = 0, a4 = 0, a5 = 0, a6 = 0, a7 = 0;
  for (; i + 1 < s1; i += 2) {
    int e0 = esrc[i], e1 = esrc[i + 1];
    uint4 r0 = *(const uint4*)(m + (size_t)e0 * 256 + l * 8);
    uint4 r1 = *(const uint4*)(m + (size_t)e1 * 256 + l * 8);
    MRG(r0); MRG(r1);
  }
  if (i < s1) {
    uint4 r0 = *(const uint4*)(m + (size_t)esrc[i] * 256 + l * 8);
    MRG(r0);
  }
  uint4 w;
  w.x = a0 | (a1 << 16); w.y = a2 | (a3 << 16);
  w.z = a4 | (a5 << 16); w.w = a6 | (a7 << 16);
  *(uint4*)(out + (size_t)n * 256 + l * 8) = w;
}
#undef MRG

// ---------------- generic MFMA GEMM: C = act(concat(A0,A1) @ Bt^T + bias) ----------------
__global__ __launch_bounds__(256) void gemm_mfma(
    const u16* __restrict__ A0, const u16* __restrict__ A1, int K0, int K1,
    const u16* __restrict__ Bt, const u16* __restrict__ bias, int do_relu,
    u16* __restrict__ C, float* __restrict__ Cf, const int* __restrict__ flag,
    int M, int Nld) {
  __shared__ __align__(16) u16 As[128 * 40];
  __shared__ __align__(16) u16 Bs[128 * 40];
  const int t = threadIdx.x;
  const int lane = t & 63, wv = t >> 6;
  const int wm = wv & 1, wn = wv >> 1;
  const int r = lane & 15, q = lane >> 4;
  const int bm = blockIdx.x, bn = blockIdx.y;
  const int Ktot = K0 + K1;
  const bool usef = (Cf != nullptr) && (*flag != 0);

  f32x4 acc[4][4];
#pragma unroll
  for (int i = 0; i < 4; i++)
#pragma unroll
    for (int j = 0; j < 4; j++) acc[i][j] = (f32x4){0.f, 0.f, 0.f, 0.f};

  for (int kc = 0; kc < Ktot; kc += 32) {
#pragma unroll
    for (int h = 0; h < 2; h++) {
      int idx = t + h * 256;          // 0..511
      int rr = idx >> 2, qq = idx & 3;
      int rowg = bm * 128 + rr;
      uint4 av = make_uint4(0, 0, 0, 0);
      if (rowg < M) {
        const u16* p = (kc < K0) ? (A0 + (size_t)rowg * K0 + kc)
                                 : (A1 + (size_t)rowg * K1 + (kc - K0));
        av = *(const uint4*)(p + qq * 8);
      }
      *(uint4*)&As[rr * 40 + qq * 8] = av;
      int ng = bn * 128 + rr;
      uint4 bv = *(const uint4*)(Bt + (size_t)ng * Ktot + kc + qq * 8);
      *(uint4*)&Bs[rr * 40 + qq * 8] = bv;
    }
    __syncthreads();
    bf16x8 af[4], bfm[4];
#pragma unroll
    for (int mi = 0; mi < 4; mi++)
      af[mi] = *(const bf16x8*)&As[(wm * 64 + mi * 16 + r) * 40 + q * 8];
#pragma unroll
    for (int ni = 0; ni < 4; ni++)
      bfm[ni] = *(const bf16x8*)&Bs[(wn * 64 + ni * 16 + r) * 40 + q * 8];
#pragma unroll
    for (int mi = 0; mi < 4; mi++)
#pragma unroll
      for (int ni = 0; ni < 4; ni++)
        acc[mi][ni] = __builtin_amdgcn_mfma_f32_16x16x32_bf16(af[mi], bfm[ni], acc[mi][ni], 0, 0, 0);
    __syncthreads();
  }

  float bv[4];
#pragma unroll
  for (int ni = 0; ni < 4; ni++)
    bv[ni] = bias ? b2f(bias[bn * 128 + wn * 64 + ni * 16 + r]) : 0.f;
#pragma unroll
  for (int mi = 0; mi < 4; mi++) {
#pragma unroll
    for (int i = 0; i < 4; i++) {
      int rowg = bm * 128 + wm * 64 + mi * 16 + q * 4 + i;
      if (rowg >= M) continue;
#pragma unroll
      for (int ni = 0; ni < 4; ni++) {
        int colg = bn * 128 + wn * 64 + ni * 16 + r;
        float v = acc[mi][ni][i] + bv[ni];
        if (do_relu) v = v > 0.f ? v : 0.f;
        if (usef) Cf[(size_t)rowg * Nld + colg] = v;
        else C[(size_t)rowg * Nld + colg] = f2b(v);
      }
    }
  }
}

// ---------------- node head: node_pred = LN(h1@W + b), smb32 = [softmax | 0-pad] ----------------
__global__ __launch_bounds__(256) void node_head(
    const u16* __restrict__ h1, const u16* __restrict__ W, const u16* __restrict__ b,
    const u16* __restrict__ g, const u16* __restrict__ beta,
    u16* __restrict__ outN, float* __restrict__ outNf, const int* __restrict__ flag,
    u16* __restrict__ smOut) {
  __shared__ float Wl[256 * 5];
  __shared__ float bl[5], gl[5], betal[5];
  int t = threadIdx.x;
#pragma unroll
  for (int c = 0; c < 5; c++) Wl[t * 5 + c] = b2f(W[t * 5 + c]);
  if (t < 5) { bl[t] = b2f(b[t]); gl[t] = b2f(g[t]); betal[t] = b2f(beta[t]); }
  __syncthreads();
  int n = blockIdx.x * 256 + t;
  if (n >= N_NODES) return;
  const bool usef = (*flag != 0);
  float acc[5] = {0.f, 0.f, 0.f, 0.f, 0.f};
  const u16* hp = h1 + (size_t)n * 256;
  for (int k8 = 0; k8 < 32; k8++) {
    uint4 v = *(const uint4*)(hp + k8 * 8);
    u32 wds[4] = {v.x, v.y, v.z, v.w};
#pragma unroll
    for (int h = 0; h < 4; h++) {
      float x0 = b2f_lo(wds[h]), x1 = b2f_hi(wds[h]);
      int k = k8 * 8 + h * 2;
#pragma unroll
      for (int c = 0; c < 5; c++)
        acc[c] += x0 * Wl[k * 5 + c] + x1 * Wl[(k + 1) * 5 + c];
    }
  }
  float x[5], mu = 0.f;
#pragma unroll
  for (int c = 0; c < 5; c++) { x[c] = acc[c] + bl[c]; mu += x[c]; }
  mu *= 0.2f;
  float var = 0.f;
#pragma unroll
  for (int c = 0; c < 5; c++) { float d = x[c] - mu; var += d * d; }
  var *= 0.2f;
  float rstd = rsqrtf(fmaxf(var, 0.f) + 1e-5f);
  float v5[5], mx = -1e30f;
#pragma unroll
  for (int c = 0; c < 5; c++) {
    v5[c] = gl[c] * (x[c] - mu) * rstd + betal[c];
    if (usef) outNf[(size_t)n * 5 + c] = v5[c];
    else outN[(size_t)n * 5 + c] = f2b(v5[c]);
    mx = fmaxf(mx, v5[c]);
  }
  float s = 0.f, ex[5];
#pragma unroll
  for (int c = 0; c < 5; c++) { ex[c] = __expf(v5[c] - mx); s += ex[c]; }
  float inv = 1.f / s;
  u16 row[32];
#pragma unroll
  for (int c = 0; c < 5; c++) row[c] = f2b(ex[c] * inv);
#pragma unroll
  for (int c = 5; c < 32; c++) row[c] = 0;
#pragma unroll
  for (int c = 0; c < 4; c++)
    *(uint4*)(smOut + (size_t)n * 32 + c * 8) = *(const uint4*)&row[c * 8];
}

// ---------------- row sums of UV ----------------
__global__ __launch_bounds__(256) void rowsum_uv(const u16* __restrict__ UV,
                                                 float2* __restrict__ Srow) {
  int wv = threadIdx.x >> 6, lane = threadIdx.x & 63;
  int n = blockIdx.x * 4 + wv;
  if (n >= N_NODES) return;
  uint4 v = *(const uint4*)(UV + (size_t)n * 512 + lane * 8);
  float s = b2f_lo(v.x) + b2f_hi(v.x) + b2f_lo(v.y) + b2f_hi(v.y) +
            b2f_lo(v.z) + b2f_hi(v.z) + b2f_lo(v.w) + b2f_hi(v.w);
#pragma unroll
  for (int m = 1; m < 32; m <<= 1) s += __shfl_xor(s, m, 64);
  if (lane == 0) Srow[n].x = s;    // U half (lanes 0-31)
  if (lane == 32) Srow[n].y = s;   // V half (lanes 32-63)
}

// ---------------- edge mean + record pack: per PAIR of edges, 48B record ----------------
// record dwords: [0]=src0 [1]=dst0 [2]=src1 [3]=dst1 | [4]=m0 [5]=m1 [6..8]=ef0 | [9..11]=ef1
// pairs [240000, 240016) are zero-filled pad for the edge_pt record prefetch.
__global__ __launch_bounds__(256) void edge_mean(
    const int* __restrict__ src, const int* __restrict__ dst,
    const u16* __restrict__ ef, const float2* __restrict__ Srow,
    const float* __restrict__ swsum, uint4* __restrict__ recs) {
  int p = blockIdx.x * 256 + threadIdx.x;
  if (p >= 240000) {
    if (p < 240016) {
      uint4 z = make_uint4(0, 0, 0, 0);
      recs[(size_t)p * 3 + 0] = z;
      recs[(size_t)p * 3 + 1] = z;
      recs[(size_t)p * 3 + 2] = z;
    }
    return;
  }
  int e = p * 2;
  int s0 = src[e], s1 = src[e + 1];
  int d0 = dst[e], d1 = dst[e + 1];
  const u32* efp = (const u32*)(ef + (size_t)e * 6);
  u32 f0 = efp[0], f1 = efp[1], f2 = efp[2], f3 = efp[3], f4 = efp[4], f5 = efp[5];
  float xa[6] = {b2f_lo(f0), b2f_hi(f0), b2f_lo(f1), b2f_hi(f1), b2f_lo(f2), b2f_hi(f2)};
  float xb[6] = {b2f_lo(f3), b2f_hi(f3), b2f_lo(f4), b2f_hi(f4), b2f_lo(f5), b2f_hi(f5)};
  float sw[6];
#pragma unroll
  for (int k = 0; k < 6; k++) sw[k] = swsum[k];
  // EXACT same op order as the original in-loop mean computation.
  float m0 = Srow[s0].x + Srow[d0].y;
  float m1 = Srow[s1].x + Srow[d1].y;
#pragma unroll
  for (int k = 0; k < 6; k++) { m0 += xa[k] * sw[k]; m1 += xb[k] * sw[k]; }
  m0 *= (1.f / 256.f);
  m1 *= (1.f / 256.f);
  uint4 ra, rb, rc;
  ra.x = (u32)s0; ra.y = (u32)d0; ra.z = (u32)s1; ra.w = (u32)d1;
  rb.x = __float_as_uint(m0); rb.y = __float_as_uint(m1); rb.z = f0; rb.w = f1;
  rc.x = f2; rc.y = f3; rc.z = f4; rc.w = f5;
  recs[(size_t)p * 3 + 0] = ra;
  recs[(size_t)p * 3 + 1] = rb;
  recs[(size_t)p * 3 + 2] = rc;
}

// ---------------- edge pointwise v4: scalarized uniforms + packed-f32 column math ----------------
// blk_base splits the 3750-block domain across multiple dispatches (profiling granularity;
// zero numeric change).
__global__ __launch_bounds__(256) void edge_pt(
    const u16* __restrict__ UV, const uint4* __restrict__ recs,
    const u16* __restrict__ w1raw,
    const u16* __restrict__ g, const u16* __restrict__ beta,
    const u16* __restrict__ w2, const u16* __restrict__ b2,
    u16* __restrict__ outE, float* __restrict__ outEf, const int* __restrict__ flag,
    int blk_base) {
  const int t = threadIdx.x;
  const int lane = t & 63, wv = t >> 6;
  const int c0 = lane * 4;
  const int grp = (lane >> 4) & 3;  // 16-lane group id
  f32x2 wefA[6], wefB[6];           // ef->W1 rows, cols {c0,c0+1} / {c0+2,c0+3}
#pragma unroll
  for (int k = 0; k < 6; k++) {
    u32 wa = *(const u32*)(w1raw + (size_t)(261 + k) * 256 + c0);
    u32 wb = *(const u32*)(w1raw + (size_t)(261 + k) * 256 + c0 + 2);
    wefA[k] = (f32x2){b2f_lo(wa), b2f_hi(wa)};
    wefB[k] = (f32x2){b2f_lo(wb), b2f_hi(wb)};
  }
  f32x2 glA = (f32x2){b2f(g[c0]), b2f(g[c0 + 1])};
  f32x2 glB = (f32x2){b2f(g[c0 + 2]), b2f(g[c0 + 3])};
  f32x2 blA = (f32x2){b2f(beta[c0]), b2f(beta[c0 + 1])};
  f32x2 blB = (f32x2){b2f(beta[c0 + 2]), b2f(beta[c0 + 3])};
  float w20[4], w21[4];
#pragma unroll
  for (int j = 0; j < 4; j++) {
    w20[j] = b2f(w2[(c0 + j) * 2]); w21[j] = b2f(w2[(c0 + j) * 2 + 1]);
  }
  const float b20 = b2f(b2[0]), b21 = b2f(b2[1]);
  const float bsel = (grp & 1) ? b21 : b20;
  const bool usef = (*flag != 0);
  const f32x2 zero2 = (f32x2){0.f, 0.f};

  // pair index base — force uniform so record loads become s_load
  const int pb = __builtin_amdgcn_readfirstlane(((blk_base + blockIdx.x) * 4 + wv) * 16);
  const uint4* rp = recs + (size_t)pb * 3;
  uint4 ra = rp[0], rb = rp[1], rc = rp[2];
#pragma unroll 1
  for (int it = 0; it < 16; ++it) {
    const int e = (pb + it) * 2;
    uint4 ca = ra, cb = rb, cc = rc;
    // prefetch next record (tail over-read lands in zero-filled pad)
    ra = rp[3 * it + 3]; rb = rp[3 * it + 4]; rc = rp[3 * it + 5];
    const int s0 = (int)ca.x, d0 = (int)ca.y, s1 = (int)ca.z, d1 = (int)ca.w;
    const float ma = __uint_as_float(cb.x), mb = __uint_as_float(cb.y);
    float xa[6] = {b2f_lo(cb.z), b2f_hi(cb.z), b2f_lo(cb.w), b2f_hi(cb.w),
                   b2f_lo(cc.x), b2f_hi(cc.x)};
    float xb[6] = {b2f_lo(cc.y), b2f_hi(cc.y), b2f_lo(cc.z), b2f_hi(cc.z),
                   b2f_lo(cc.w), b2f_hi(cc.w)};
    // UV gathers: SGPR base + constant per-lane offset
    uint2 ua = *(const uint2*)(UV + ((size_t)(u32)s0 << 9) + c0);
    uint2 va = *(const uint2*)(UV + ((size_t)(u32)d0 << 9) + 256 + c0);
    uint2 ub = *(const uint2*)(UV + ((size_t)(u32)s1 << 9) + c0);
    uint2 vb = *(const uint2*)(UV + ((size_t)(u32)d1 << 9) + 256 + c0);

    f32x2 yaA = (f32x2){b2f_lo(ua.x), b2f_hi(ua.x)} + (f32x2){b2f_lo(va.x), b2f_hi(va.x)};
    f32x2 yaB = (f32x2){b2f_lo(ua.y), b2f_hi(ua.y)} + (f32x2){b2f_lo(va.y), b2f_hi(va.y)};
    f32x2 ybA = (f32x2){b2f_lo(ub.x), b2f_hi(ub.x)} + (f32x2){b2f_lo(vb.x), b2f_hi(vb.x)};
    f32x2 ybB = (f32x2){b2f_lo(ub.y), b2f_hi(ub.y)} + (f32x2){b2f_lo(vb.y), b2f_hi(vb.y)};
#pragma unroll
    for (int k = 0; k < 6; k++) {
      yaA += xa[k] * wefA[k];
      yaB += xa[k] * wefB[k];
      ybA += xb[k] * wefA[k];
      ybB += xb[k] * wefB[k];
    }
    // sum of squares — original scalar association
    float pqa = yaA.x * yaA.x;
    pqa += yaA.y * yaA.y; pqa += yaB.x * yaB.x; pqa += yaB.y * yaB.y;
    float pqb = ybA.x * ybA.x;
    pqb += ybA.y * ybA.y; pqb += ybB.x * ybB.x; pqb += ybB.y * ybB.y;
    pqa += __shfl_xor(pqa, 32, 64);
    pqb += __shfl_xor(pqb, 32, 64);
    float z = (lane < 32) ? pqa : pqb;
#pragma unroll
    for (int m = 16; m >= 1; m >>= 1) z += __shfl_xor(z, m, 64);
    float zz = __shfl_xor(z, 32, 64);
    float pqa_t = (lane < 32) ? z : zz;
    float pqb_t = (lane < 32) ? zz : z;
    float rsa = rsqrtf(fmaxf(pqa_t * (1.f / 256.f) - ma * ma, 0.f) + 1e-5f);
    float rsb = rsqrtf(fmaxf(pqb_t * (1.f / 256.f) - mb * mb, 0.f) + 1e-5f);
    // LN + relu, packed (elementwise ops identical to scalar version)
    f32x2 nAa = __builtin_elementwise_max((yaA - ma) * rsa * glA + blA, zero2);
    f32x2 nAb = __builtin_elementwise_max((yaB - ma) * rsa * glB + blB, zero2);
    f32x2 nBa = __builtin_elementwise_max((ybA - mb) * rsb * glA + blA, zero2);
    f32x2 nBb = __builtin_elementwise_max((ybB - mb) * rsb * glB + blB, zero2);
    // final 2-wide matvec — original scalar association
    float p0a = nAa.x * w20[0], p1a = nAa.x * w21[0];
    p0a += nAa.y * w20[1]; p1a += nAa.y * w21[1];
    p0a += nAb.x * w20[2]; p1a += nAb.x * w21[2];
    p0a += nAb.y * w20[3]; p1a += nAb.y * w21[3];
    float p0b = nBa.x * w20[0], p1b = nBa.x * w21[0];
    p0b += nBa.y * w20[1]; p1b += nBa.y * w21[1];
    p0b += nBb.x * w20[2]; p1b += nBb.x * w21[2];
    p0b += nBb.y * w20[3]; p1b += nBb.y * w21[3];
    p0a += __shfl_xor(p0a, 32, 64); p1a += __shfl_xor(p1a, 32, 64);
    p0b += __shfl_xor(p0b, 32, 64); p1b += __shfl_xor(p1b, 32, 64);
    p0a += __shfl_xor(p0a, 16, 64); p1a += __shfl_xor(p1a, 16, 64);
    p0b += __shfl_xor(p0b, 16, 64); p1b += __shfl_xor(p1b, 16, 64);
    float w = (grp & 2) ? ((grp & 1) ? p1b : p0b) : ((grp & 1) ? p1a : p0a);
#pragma unroll
    for (int m = 8; m >= 1; m >>= 1) w += __shfl_xor(w, m, 64);
    if ((lane & 15) == 0) {
      float val = w + bsel;
      size_t oi = (size_t)e * 2 + grp;
      if (usef) outEf[oi] = val;
      else outE[oi] = f2b(val);
    }
  }
}

extern "C" void kernel_launch(void* const* d_in, const int* in_sizes, int n_in,
                              void* d_out, int out_size, void* d_ws, size_t ws_size,
                              hipStream_t stream) {
  char* wp = (char*)d_ws;
  auto alloc = [&](size_t bytes) -> char* {
    char* p = wp; wp += (bytes + 255) & ~(size_t)255; return p;
  };
  int* flag       = (int*)alloc(256);
  u16* c_h        = (u16*)alloc((size_t)N_NODES * 128 * 2);
  u16* c_ef       = (u16*)alloc((size_t)N_EDGES * 6 * 2);
  static const int pidx[20] = {4,5,6,7,8, 9,10,11,12, 13,14,15,16,17,18, 19,20,21,22,23};
  static const int pn[20]   = {16384,128,32768,256,32768, 1280,5,5,5,
                               135168,256,256,256,512,2, 65536,256,32768,128,32768};
  u16* cp[20];
  for (int a = 0; a < 20; a++) cp[a] = (u16*)alloc((size_t)pn[a] * 2);

  u16* wt_encpool = (u16*)alloc(128 * 128 * 2);
  u16* wt_enc     = (u16*)alloc(256 * 256 * 2);
  u16* wt_decpool = (u16*)alloc(256 * 256 * 2);
  u16* wt_dec     = (u16*)alloc(128 * 512 * 2);
  u16* wt_UV      = (u16*)alloc(512 * 288 * 2);
  u16* b512       = (u16*)alloc(512 * 2);
  float2* Srow    = (float2*)alloc((size_t)N_NODES * 8);
  float* swsum_b  = (float*)alloc(64);
  u16* m_buf      = (u16*)alloc((size_t)N_NODES * 256 * 2);
  u16* aggb       = (u16*)alloc((size_t)N_NODES * 256 * 2);
  u16* UVbuf      = m_buf;  // m_buf+aggb contiguous => [N][512] during edge phase
  u16* h1b        = (u16*)alloc((size_t)N_NODES * 256 * 2);
  u16* smb32      = (u16*)alloc((size_t)N_NODES * 32 * 2);
  int* deg        = (int*)alloc((size_t)N_NODES * 4);
  int* off        = (int*)alloc((size_t)(N_NODES + 1) * 4);
  int* cursor     = (int*)alloc((size_t)N_NODES * 4);
  int* esrc       = (int*)alloc((size_t)N_EDGES * 4);
  uint4* recs     = (uint4*)alloc(((size_t)240000 * 3 + 64) * 16);  // 48B/pair + pad

  const int* src = (const int*)d_in[2];
  const int* dst = (const int*)d_in[3];

  u16* outN = (u16*)d_out;
  u16* outE = outN + (size_t)N_NODES * 5;
  u16* outH = outN + 1110000;
  float* outNf = (float*)d_out;
  float* outEf = outNf + (size_t)N_NODES * 5;
  float* outHf = outNf + 1110000;

  // --- init (deg zero + dtype sniff) ---
  init_sniff_deg<<<118, 256, 0, stream>>>((const u16*)d_in[0], flag, deg);
  // --- fused front-end: deg_count + all conversions ---
  ConvTab tab;
  int off_a = 0;
  for (int a = 0; a < 20; a++) {
    tab.e[a].s = d_in[pidx[a]]; tab.e[a].d = cp[a]; tab.e[a].n = pn[a]; tab.e[a].off = off_a;
    off_a += pn[a];
  }
  tab.total = off_a;
  int conv_blocks = 1875 + 3750 + 2813 + (off_a + 255) / 256;
  conv_all<<<conv_blocks, 256, 0, stream>>>(dst, deg, d_in[0], c_h, d_in[1], c_ef, tab, flag);

  const u16 *enc_Wpool = cp[0], *enc_bpool = cp[1], *enc_Wself = cp[2], *enc_bself = cp[3],
            *enc_Wneigh = cp[4], *np_W = cp[5], *np_b = cp[6], *np_g = cp[7], *np_beta = cp[8],
            *ep_W1 = cp[9], *ep_b1 = cp[10], *ep_g = cp[11], *ep_beta = cp[12],
            *ep_W2 = cp[13], *ep_b2 = cp[14], *dec_Wpool = cp[15], *dec_bpool = cp[16],
            *dec_Wself = cp[17], *dec_bself = cp[18], *dec_Wneigh = cp[19];

  // --- CSR scan, then merged fill_csr + weight prep ---
  scan_off<<<1, 1024, 0, stream>>>(deg, off, cursor, N_NODES);
  fill_prep<<<1875 + 1347, 256, 0, stream>>>(src, dst, cursor, esrc,
                                             enc_Wpool, enc_Wself, enc_Wneigh,
                                             dec_Wpool, dec_Wself, dec_Wneigh,
                                             ep_W1, ep_b1,
                                             wt_encpool, wt_enc, wt_decpool, wt_dec,
                                             wt_UV, b512, swsum_b);

  // --- encoder ---
  gemm_mfma<<<dim3(235, 1), 256, 0, stream>>>(c_h, nullptr, 128, 0, wt_encpool,
                                              enc_bpool, 1, m_buf, nullptr, flag, N_NODES, 128);
  agg128<<<1875, 256, 0, stream>>>(m_buf, esrc, off, aggb);
  gemm_mfma<<<dim3(235, 2), 256, 0, stream>>>(c_h, aggb, 128, 128, wt_enc,
                                              enc_bself, 1, h1b, nullptr, flag, N_NODES, 256);
  // --- node head ---
  node_head<<<118, 256, 0, stream>>>(h1b, np_W, np_b, np_g, np_beta, outN, outNf, flag, smb32);
  // --- edge head: UV GEMM -> row sums -> edge means -> pointwise (4 profiling splits) ---
  gemm_mfma<<<dim3(235, 4), 256, 0, stream>>>(h1b, smb32, 256, 32, wt_UV,
                                              b512, 0, UVbuf, nullptr, flag, N_NODES, 512);
  rowsum_uv<<<7500, 256, 0, stream>>>(UVbuf, Srow);
  edge_mean<<<938, 256, 0, stream>>>(src, dst, c_ef, Srow, swsum_b, recs);
  edge_pt<<<938, 256, 0, stream>>>(UVbuf, recs, ep_W1, ep_g, ep_beta, ep_W2, ep_b2,
                                   outE, outEf, flag, 0);
  edge_pt<<<938, 256, 0, stream>>>(UVbuf, recs, ep_W1, ep_g, ep_beta, ep_W2, ep_b2,
                                   outE, outEf, flag, 938);
  edge_pt<<<938, 256, 0, stream>>>(UVbuf, recs, ep_W1, ep_g, ep_beta, ep_W2, ep_b2,
                                   outE, outEf, flag, 1876);
  edge_pt<<<936, 256, 0, stream>>>(UVbuf, recs, ep_W1, ep_g, ep_beta, ep_W2, ep_b2,
                                   outE, outEf, flag, 2814);
  // --- decoder ---
  gemm_mfma<<<dim3(235, 2), 256, 0, stream>>>(h1b, nullptr, 256, 0, wt_decpool,
                                              dec_bpool, 1, m_buf, nullptr, flag, N_NODES, 256);
  agg256<<<3750, 256, 0, stream>>>(m_buf, esrc, off, aggb);
  gemm_mfma<<<dim3(235, 1), 256, 0, stream>>>(h1b, aggb, 256, 256, wt_dec,
                                              dec_bself, 1, outH, outHf, flag, N_NODES, 128);
}

// Round 7
// 477.218 us; speedup vs baseline: 1.0425x; 1.0425x over previous
//
#include <hip/hip_runtime.h>

typedef unsigned short u16;
typedef unsigned int u32;
typedef __bf16 bf16_t;
typedef bf16_t bf16x8 __attribute__((ext_vector_type(8)));
typedef float f32x4 __attribute__((ext_vector_type(4)));
typedef float f32x2 __attribute__((ext_vector_type(2)));

#define N_NODES 30000
#define N_EDGES 480000

static __device__ __forceinline__ float b2f(u16 u) {
  return __uint_as_float(((u32)u) << 16);
}
static __device__ __forceinline__ float b2f_lo(u32 w) {
  return __uint_as_float(w << 16);
}
static __device__ __forceinline__ float b2f_hi(u32 w) {
  return __uint_as_float(w & 0xffff0000u);
}
static __device__ __forceinline__ u16 f2b(float f) {
  u32 x = __float_as_uint(f);
  u32 r = (x + 0x7fffu + ((x >> 16) & 1u)) >> 16;
  return (u16)r;
}

// ---------------- init: zero deg; block 0 sniffs dtype (bf16=0 / f32=1) ----------------
__global__ __launch_bounds__(256) void init_sniff_deg(const u16* __restrict__ h,
                                                      int* __restrict__ flag,
                                                      int* __restrict__ deg) {
  int i = blockIdx.x * 256 + threadIdx.x;
  if (i < N_NODES) deg[i] = 0;
  if (blockIdx.x == 0) {
    int t = threadIdx.x;
    int bad = 0;
#pragma unroll
    for (int j = 0; j < 4; j++) {
      u32 e = ((u32)h[t * 4 + j] >> 7) & 0xFFu;
      if (e >= 0x8Eu) bad = 1;  // impossible magnitude for N(0,1) bf16 data
    }
    int r = __syncthreads_or(bad);
    if (t == 0) *flag = r ? 1 : 0;
  }
}

struct ConvDesc { const void* s; u16* d; int n; int off; };
struct ConvTab { ConvDesc e[20]; int total; };

// ---------------- fused front-end: deg_count | conv h | conv ef | conv params ----------------
__global__ __launch_bounds__(256) void conv_all(
    const int* __restrict__ dstE, int* __restrict__ deg,
    const void* __restrict__ hsrc, u16* __restrict__ c_h,
    const void* __restrict__ efsrc, u16* __restrict__ c_ef,
    ConvTab tab, const int* __restrict__ flag) {
  int b = blockIdx.x;
  const int t = threadIdx.x;
  if (b < 1875) {
    int e = b * 256 + t;
    if (e < N_EDGES) atomicAdd(&deg[dstE[e]], 1);
    return;
  }
  b -= 1875;
  const int f = *flag;
  if (b < 3750) {  // h: 960000 uint2-groups
    int i = b * 256 + t;
    if (f) {
      float4 v = ((const float4*)hsrc)[i];
      uint2 o;
      o.x = (u32)f2b(v.x) | ((u32)f2b(v.y) << 16);
      o.y = (u32)f2b(v.z) | ((u32)f2b(v.w) << 16);
      ((uint2*)c_h)[i] = o;
    } else {
      ((uint2*)c_h)[i] = ((const uint2*)hsrc)[i];
    }
    return;
  }
  b -= 3750;
  if (b < 2813) {  // ef: 720000 4-elem groups
    int i = b * 256 + t;
    if (i < 720000) {
      if (f) {
        float4 v = ((const float4*)efsrc)[i];
        uint2 o;
        o.x = (u32)f2b(v.x) | ((u32)f2b(v.y) << 16);
        o.y = (u32)f2b(v.z) | ((u32)f2b(v.w) << 16);
        ((uint2*)c_ef)[i] = o;
      } else {
        ((uint2*)c_ef)[i] = ((const uint2*)efsrc)[i];
      }
    }
    return;
  }
  b -= 2813;
  int i = b * 256 + t;
  if (i >= tab.total) return;
#pragma unroll 1
  for (int a = 0; a < 20; a++) {
    int j = i - tab.e[a].off;
    if (j >= 0 && j < tab.e[a].n) {
      if (f) tab.e[a].d[j] = f2b(((const float*)tab.e[a].s)[j]);
      else tab.e[a].d[j] = ((const u16*)tab.e[a].s)[j];
      return;
    }
  }
}

__global__ __launch_bounds__(1024) void scan_off(const int* __restrict__ deg,
                                                 int* __restrict__ off,
                                                 int* __restrict__ cursor, int n) {
  __shared__ int carry;
  __shared__ int wsum[16];
  int t = threadIdx.x, lane = t & 63, wv = t >> 6;
  if (t == 0) { carry = 0; off[0] = 0; }
  __syncthreads();
  for (int base = 0; base < n; base += 1024) {
    int v = (base + t < n) ? deg[base + t] : 0;
    int x = v;
#pragma unroll
    for (int d = 1; d < 64; d <<= 1) {
      int y = __shfl_up(x, d, 64);
      if (lane >= d) x += y;
    }
    if (lane == 63) wsum[wv] = x;
    __syncthreads();
    int wadd = 0;
    for (int w = 0; w < wv; w++) wadd += wsum[w];
    int incl = x + wadd + carry;
    if (base + t < n) { off[base + t + 1] = incl; cursor[base + t] = incl - v; }
    __syncthreads();
    if (t == 1023) carry = incl;
    __syncthreads();
  }
}

// fill_csr + epos: epos[e] = CSR slot of original edge e (for CSR-ordered edge records)
__global__ __launch_bounds__(256) void fill_csr(const int* __restrict__ src,
                                                const int* __restrict__ dst,
                                                int* __restrict__ cursor,
                                                int* __restrict__ esrc,
                                                int* __restrict__ epos, int nE) {
  int e = blockIdx.x * 256 + threadIdx.x;
  if (e >= nE) return;
  int p = atomicAdd(&cursor[dst[e]], 1);
  esrc[p] = src[e];
  epos[e] = p;
}

#define MRG(r)                                                    \
  do {                                                            \
    a0 = max(a0, (r).x & 0xffffu); a1 = max(a1, (r).x >> 16);     \
    a2 = max(a2, (r).y & 0xffffu); a3 = max(a3, (r).y >> 16);     \
    a4 = max(a4, (r).z & 0xffffu); a5 = max(a5, (r).z >> 16);     \
    a6 = max(a6, (r).w & 0xffffu); a7 = max(a7, (r).w >> 16);     \
  } while (0)

// ---------------- CSR max-aggregate (unsigned max == float max for bf16 >= 0) ----------------
// 4 nodes per wave; 16 lanes x uint4 per row (128 cols).
__global__ __launch_bounds__(256) void agg128(const u16* __restrict__ m,
                                              const int* __restrict__ esrc,
                                              const int* __restrict__ off,
                                              u16* __restrict__ out) {
  int wv = threadIdx.x >> 6, lane = threadIdx.x & 63;
  int qd = lane >> 4, l = lane & 15;
  int n = blockIdx.x * 16 + wv * 4 + qd;
  if (n >= N_NODES) return;
  int i = off[n], s1 = off[n + 1];
  u32 a0 = 0, a1 = 0, a2 = 0, a3 = 0, a4 = 0, a5 = 0, a6 = 0, a7 = 0;
  for (; i + 1 < s1; i += 2) {
    int e0 = esrc[i], e1 = esrc[i + 1];
    uint4 r0 = *(const uint4*)(m + (size_t)e0 * 128 + l * 8);
    uint4 r1 = *(const uint4*)(m + (size_t)e1 * 128 + l * 8);
    MRG(r0); MRG(r1);
  }
  if (i < s1) {
    uint4 r0 = *(const uint4*)(m + (size_t)esrc[i] * 128 + l * 8);
    MRG(r0);
  }
  uint4 w;
  w.x = a0 | (a1 << 16); w.y = a2 | (a3 << 16);
  w.z = a4 | (a5 << 16); w.w = a6 | (a7 << 16);
  *(uint4*)(out + (size_t)n * 128 + l * 8) = w;
}

// 2 nodes per wave; 32 lanes x uint4 per row (256 cols).
__global__ __launch_bounds__(256) void agg256(const u16* __restrict__ m,
                                              const int* __restrict__ esrc,
                                              const int* __restrict__ off,
                                              u16* __restrict__ out) {
  int wv = threadIdx.x >> 6, lane = threadIdx.x & 63;
  int half = lane >> 5, l = lane & 31;
  int n = blockIdx.x * 8 + wv * 2 + half;
  if (n >= N_NODES) return;
  int i = off[n], s1 = off[n + 1];
  u32 a0 = 0, a1 = 0, a2 = 0, a3 = 0, a4 = 0, a5 = 0, a6 = 0, a7 = 0;
  for (; i + 1 < s1; i += 2) {
    int e0 = esrc[i], e1 = esrc[i + 1];
    uint4 r0 = *(const uint4*)(m + (size_t)e0 * 256 + l * 8);
    uint4 r1 = *(const uint4*)(m + (size_t)e1 * 256 + l * 8);
    MRG(r0); MRG(r1);
  }
  if (i < s1) {
    uint4 r0 = *(const uint4*)(m + (size_t)esrc[i] * 256 + l * 8);
    MRG(r0);
  }
  uint4 w;
  w.x = a0 | (a1 << 16); w.y = a2 | (a3 << 16);
  w.z = a4 | (a5 << 16); w.w = a6 | (a7 << 16);
  *(uint4*)(out + (size_t)n * 256 + l * 8) = w;
}
#undef MRG

// ---------------- fused weight prep: all transposes + UV build + b512 + wefsum ----------------
__global__ __launch_bounds__(256) void prep_weights(
    const u16* __restrict__ encWp, const u16* __restrict__ encWs, const u16* __restrict__ encWn,
    const u16* __restrict__ decWp, const u16* __restrict__ decWs, const u16* __restrict__ decWn,
    const u16* __restrict__ epW1, const u16* __restrict__ epb1,
    u16* __restrict__ wt_encpool, u16* __restrict__ wt_enc,
    u16* __restrict__ wt_decpool, u16* __restrict__ wt_dec,
    u16* __restrict__ wt_UV, u16* __restrict__ b512, float* __restrict__ swsum) {
  int b = blockIdx.x;
  const int t = threadIdx.x;
  if (b < 64) {
    int idx = b * 256 + t; int k = idx >> 7, n = idx & 127;
    wt_encpool[n * 128 + k] = encWp[k * 128 + n]; return;
  }
  b -= 64;
  if (b < 128) {
    int idx = b * 256 + t; int k = idx >> 8, n = idx & 255;
    wt_enc[n * 256 + k] = encWs[k * 256 + n]; return;
  }
  b -= 128;
  if (b < 128) {
    int idx = b * 256 + t; int k = idx >> 8, n = idx & 255;
    wt_enc[n * 256 + 128 + k] = encWn[k * 256 + n]; return;
  }
  b -= 128;
  if (b < 256) {
    int idx = b * 256 + t; int k = idx >> 8, n = idx & 255;
    wt_decpool[n * 256 + k] = decWp[k * 256 + n]; return;
  }
  b -= 256;
  if (b < 128) {
    int idx = b * 256 + t; int k = idx >> 7, n = idx & 127;
    wt_dec[n * 512 + k] = decWs[k * 128 + n]; return;
  }
  b -= 128;
  if (b < 128) {
    int idx = b * 256 + t; int k = idx >> 7, n = idx & 127;
    wt_dec[n * 512 + 256 + k] = decWn[k * 128 + n]; return;
  }
  b -= 128;
  if (b < 512) {
    int n = b, n2 = n & 255, base = (n >= 256) ? 267 : 0;
    for (int kp = t; kp < 288; kp += 256) {
      u16 v = (kp < 261) ? epW1[(size_t)(base + kp) * 256 + n2] : (u16)0;
      wt_UV[(size_t)n * 288 + kp] = v;
    }
    return;
  }
  b -= 512;
  if (b < 2) {
    int i = b * 256 + t;
    b512[i] = (i < 256) ? epb1[i] : (u16)0; return;
  }
  int k = t >> 5, l32 = t & 31;
  if (k < 6) {
    uint4 v = *(const uint4*)(epW1 + (size_t)(261 + k) * 256 + l32 * 8);
    float s = b2f_lo(v.x) + b2f_hi(v.x) + b2f_lo(v.y) + b2f_hi(v.y) +
              b2f_lo(v.z) + b2f_hi(v.z) + b2f_lo(v.w) + b2f_hi(v.w);
#pragma unroll
    for (int m = 1; m < 32; m <<= 1) s += __shfl_xor(s, m, 64);
    if (l32 == 0) swsum[k] = s;
  }
}

// ---------------- generic MFMA GEMM: C = act(concat(A0,A1) @ Bt^T + bias) ----------------
__global__ __launch_bounds__(256) void gemm_mfma(
    const u16* __restrict__ A0, const u16* __restrict__ A1, int K0, int K1,
    const u16* __restrict__ Bt, const u16* __restrict__ bias, int do_relu,
    u16* __restrict__ C, float* __restrict__ Cf, const int* __restrict__ flag,
    int M, int Nld) {
  __shared__ __align__(16) u16 As[128 * 40];
  __shared__ __align__(16) u16 Bs[128 * 40];
  const int t = threadIdx.x;
  const int lane = t & 63, wv = t >> 6;
  const int wm = wv & 1, wn = wv >> 1;
  const int r = lane & 15, q = lane >> 4;
  const int bm = blockIdx.x, bn = blockIdx.y;
  const int Ktot = K0 + K1;
  const bool usef = (Cf != nullptr) && (*flag != 0);

  f32x4 acc[4][4];
#pragma unroll
  for (int i = 0; i < 4; i++)
#pragma unroll
    for (int j = 0; j < 4; j++) acc[i][j] = (f32x4){0.f, 0.f, 0.f, 0.f};

  for (int kc = 0; kc < Ktot; kc += 32) {
#pragma unroll
    for (int h = 0; h < 2; h++) {
      int idx = t + h * 256;          // 0..511
      int rr = idx >> 2, qq = idx & 3;
      int rowg = bm * 128 + rr;
      uint4 av = make_uint4(0, 0, 0, 0);
      if (rowg < M) {
        const u16* p = (kc < K0) ? (A0 + (size_t)rowg * K0 + kc)
                                 : (A1 + (size_t)rowg * K1 + (kc - K0));
        av = *(const uint4*)(p + qq * 8);
      }
      *(uint4*)&As[rr * 40 + qq * 8] = av;
      int ng = bn * 128 + rr;
      uint4 bv = *(const uint4*)(Bt + (size_t)ng * Ktot + kc + qq * 8);
      *(uint4*)&Bs[rr * 40 + qq * 8] = bv;
    }
    __syncthreads();
    bf16x8 af[4], bfm[4];
#pragma unroll
    for (int mi = 0; mi < 4; mi++)
      af[mi] = *(const bf16x8*)&As[(wm * 64 + mi * 16 + r) * 40 + q * 8];
#pragma unroll
    for (int ni = 0; ni < 4; ni++)
      bfm[ni] = *(const bf16x8*)&Bs[(wn * 64 + ni * 16 + r) * 40 + q * 8];
#pragma unroll
    for (int mi = 0; mi < 4; mi++)
#pragma unroll
      for (int ni = 0; ni < 4; ni++)
        acc[mi][ni] = __builtin_amdgcn_mfma_f32_16x16x32_bf16(af[mi], bfm[ni], acc[mi][ni], 0, 0, 0);
    __syncthreads();
  }

  float bv[4];
#pragma unroll
  for (int ni = 0; ni < 4; ni++)
    bv[ni] = bias ? b2f(bias[bn * 128 + wn * 64 + ni * 16 + r]) : 0.f;
#pragma unroll
  for (int mi = 0; mi < 4; mi++) {
#pragma unroll
    for (int i = 0; i < 4; i++) {
      int rowg = bm * 128 + wm * 64 + mi * 16 + q * 4 + i;
      if (rowg >= M) continue;
#pragma unroll
      for (int ni = 0; ni < 4; ni++) {
        int colg = bn * 128 + wn * 64 + ni * 16 + r;
        float v = acc[mi][ni][i] + bv[ni];
        if (do_relu) v = v > 0.f ? v : 0.f;
        if (usef) Cf[(size_t)rowg * Nld + colg] = v;
        else C[(size_t)rowg * Nld + colg] = f2b(v);
      }
    }
  }
}

// ---------------- node head: node_pred = LN(h1@W + b), smb32 = [softmax | 0-pad] ----------------
__global__ __launch_bounds__(256) void node_head(
    const u16* __restrict__ h1, const u16* __restrict__ W, const u16* __restrict__ b,
    const u16* __restrict__ g, const u16* __restrict__ beta,
    u16* __restrict__ outN, float* __restrict__ outNf, const int* __restrict__ flag,
    u16* __restrict__ smOut) {
  __shared__ float Wl[256 * 5];
  __shared__ float bl[5], gl[5], betal[5];
  int t = threadIdx.x;
#pragma unroll
  for (int c = 0; c < 5; c++) Wl[t * 5 + c] = b2f(W[t * 5 + c]);
  if (t < 5) { bl[t] = b2f(b[t]); gl[t] = b2f(g[t]); betal[t] = b2f(beta[t]); }
  __syncthreads();
  int n = blockIdx.x * 256 + t;
  if (n >= N_NODES) return;
  const bool usef = (*flag != 0);
  float acc[5] = {0.f, 0.f, 0.f, 0.f, 0.f};
  const u16* hp = h1 + (size_t)n * 256;
  for (int k8 = 0; k8 < 32; k8++) {
    uint4 v = *(const uint4*)(hp + k8 * 8);
    u32 wds[4] = {v.x, v.y, v.z, v.w};
#pragma unroll
    for (int h = 0; h < 4; h++) {
      float x0 = b2f_lo(wds[h]), x1 = b2f_hi(wds[h]);
      int k = k8 * 8 + h * 2;
#pragma unroll
      for (int c = 0; c < 5; c++)
        acc[c] += x0 * Wl[k * 5 + c] + x1 * Wl[(k + 1) * 5 + c];
    }
  }
  float x[5], mu = 0.f;
#pragma unroll
  for (int c = 0; c < 5; c++) { x[c] = acc[c] + bl[c]; mu += x[c]; }
  mu *= 0.2f;
  float var = 0.f;
#pragma unroll
  for (int c = 0; c < 5; c++) { float d = x[c] - mu; var += d * d; }
  var *= 0.2f;
  float rstd = rsqrtf(fmaxf(var, 0.f) + 1e-5f);
  float v5[5], mx = -1e30f;
#pragma unroll
  for (int c = 0; c < 5; c++) {
    v5[c] = gl[c] * (x[c] - mu) * rstd + betal[c];
    if (usef) outNf[(size_t)n * 5 + c] = v5[c];
    else outN[(size_t)n * 5 + c] = f2b(v5[c]);
    mx = fmaxf(mx, v5[c]);
  }
  float s = 0.f, ex[5];
#pragma unroll
  for (int c = 0; c < 5; c++) { ex[c] = __expf(v5[c] - mx); s += ex[c]; }
  float inv = 1.f / s;
  u16 row[32];
#pragma unroll
  for (int c = 0; c < 5; c++) row[c] = f2b(ex[c] * inv);
#pragma unroll
  for (int c = 5; c < 32; c++) row[c] = 0;
#pragma unroll
  for (int c = 0; c < 4; c++)
    *(uint4*)(smOut + (size_t)n * 32 + c * 8) = *(const uint4*)&row[c * 8];
}

// ---------------- row sums of UV ----------------
__global__ __launch_bounds__(256) void rowsum_uv(const u16* __restrict__ UV,
                                                 float2* __restrict__ Srow) {
  int wv = threadIdx.x >> 6, lane = threadIdx.x & 63;
  int n = blockIdx.x * 4 + wv;
  if (n >= N_NODES) return;
  uint4 v = *(const uint4*)(UV + (size_t)n * 512 + lane * 8);
  float s = b2f_lo(v.x) + b2f_hi(v.x) + b2f_lo(v.y) + b2f_hi(v.y) +
            b2f_lo(v.z) + b2f_hi(v.z) + b2f_lo(v.w) + b2f_hi(v.w);
#pragma unroll
  for (int m = 1; m < 32; m <<= 1) s += __shfl_xor(s, m, 64);
  if (lane == 0) Srow[n].x = s;    // U half (lanes 0-31)
  if (lane == 32) Srow[n].y = s;   // V half (lanes 32-63)
}

// ---------------- per-edge records in CSR order: {src, orig_e, m, ef0, ef1, ef2, 0, 0} ----------------
// One thread per ORIGINAL edge; record written at CSR slot epos[e] (32B, 2x uint4).
// m computed with the exact op order of the previous in-loop/paired version.
__global__ __launch_bounds__(256) void edge_mean(
    const int* __restrict__ src, const int* __restrict__ dst,
    const u16* __restrict__ ef, const float2* __restrict__ Srow,
    const float* __restrict__ swsum, const int* __restrict__ epos,
    uint4* __restrict__ recs) {
  int e = blockIdx.x * 256 + threadIdx.x;
  if (e >= N_EDGES) return;
  int s0 = src[e], d0 = dst[e];
  const u32* efp = (const u32*)(ef + (size_t)e * 6);
  u32 f0 = efp[0], f1 = efp[1], f2 = efp[2];
  float xa[6] = {b2f_lo(f0), b2f_hi(f0), b2f_lo(f1), b2f_hi(f1), b2f_lo(f2), b2f_hi(f2)};
  float sw[6];
#pragma unroll
  for (int k = 0; k < 6; k++) sw[k] = swsum[k];
  float m0 = Srow[s0].x + Srow[d0].y;
#pragma unroll
  for (int k = 0; k < 6; k++) m0 += xa[k] * sw[k];
  m0 *= (1.f / 256.f);
  int p = epos[e];
  uint4 r0, r1;
  r0.x = (u32)s0; r0.y = (u32)e; r0.z = __float_as_uint(m0); r0.w = f0;
  r1.x = f1; r1.y = f2; r1.z = 0; r1.w = 0;
  recs[(size_t)p * 2 + 0] = r0;
  recs[(size_t)p * 2 + 1] = r1;
}

// ---------------- edge pointwise v6: NODE-CENTRIC — V[dst] loaded once per node ----------------
// One wave per dst node, walking its CSR in-edge list in pairs. V[n] (512B) lives in
// registers for the whole list; only U[src] (512B) gathered per edge -> per-edge L3 bytes
// halved vs v4. Per-edge FP op order identical to v4 (bit-identical outputs). Odd-degree
// tail duplicates edge a into the b slot and suppresses the b-side write (a/b reduction
// lanes are independent in the tree).
__global__ __launch_bounds__(256) void edge_pt(
    const u16* __restrict__ UV, const uint4* __restrict__ recs,
    const int* __restrict__ off,
    const u16* __restrict__ w1raw,
    const u16* __restrict__ g, const u16* __restrict__ beta,
    const u16* __restrict__ w2, const u16* __restrict__ b2,
    u16* __restrict__ outE, float* __restrict__ outEf, const int* __restrict__ flag) {
  const int t = threadIdx.x;
  const int lane = t & 63;
  const int c0 = lane * 4;
  const int grp = (lane >> 4) & 3;  // 16-lane group id
  f32x2 wefA[6], wefB[6];           // ef->W1 rows, cols {c0,c0+1} / {c0+2,c0+3}
#pragma unroll
  for (int k = 0; k < 6; k++) {
    u32 wa = *(const u32*)(w1raw + (size_t)(261 + k) * 256 + c0);
    u32 wb = *(const u32*)(w1raw + (size_t)(261 + k) * 256 + c0 + 2);
    wefA[k] = (f32x2){b2f_lo(wa), b2f_hi(wa)};
    wefB[k] = (f32x2){b2f_lo(wb), b2f_hi(wb)};
  }
  f32x2 glA = (f32x2){b2f(g[c0]), b2f(g[c0 + 1])};
  f32x2 glB = (f32x2){b2f(g[c0 + 2]), b2f(g[c0 + 3])};
  f32x2 blA = (f32x2){b2f(beta[c0]), b2f(beta[c0 + 1])};
  f32x2 blB = (f32x2){b2f(beta[c0 + 2]), b2f(beta[c0 + 3])};
  float w20[4], w21[4];
#pragma unroll
  for (int j = 0; j < 4; j++) {
    w20[j] = b2f(w2[(c0 + j) * 2]); w21[j] = b2f(w2[(c0 + j) * 2 + 1]);
  }
  const float b20 = b2f(b2[0]), b21 = b2f(b2[1]);
  const float bsel = (grp & 1) ? b21 : b20;
  const bool usef = (*flag != 0);
  const f32x2 zero2 = (f32x2){0.f, 0.f};

  // node for this wave — force SGPR so off/rec loads are scalar
  const int n = __builtin_amdgcn_readfirstlane(blockIdx.x * 4 + (t >> 6));
  if (n >= N_NODES) return;
  int i = __builtin_amdgcn_readfirstlane(off[n]);
  const int s1 = __builtin_amdgcn_readfirstlane(off[n + 1]);
  if (i >= s1) return;
  // V[n] once: same unpack as v4's va
  uint2 vn = *(const uint2*)(UV + ((size_t)(u32)n << 9) + 256 + c0);
  const f32x2 vA = (f32x2){b2f_lo(vn.x), b2f_hi(vn.x)};
  const f32x2 vB = (f32x2){b2f_lo(vn.y), b2f_hi(vn.y)};

  for (; i < s1; i += 2) {
    const bool two = (i + 1 < s1);
    const int ib = two ? i + 1 : i;
    uint4 ra0 = recs[(size_t)i * 2], ra1 = recs[(size_t)i * 2 + 1];
    uint4 rb0 = recs[(size_t)ib * 2], rb1 = recs[(size_t)ib * 2 + 1];
    const int sa = (int)ra0.x, ea = (int)ra0.y;
    const int sb = (int)rb0.x, eb = (int)rb0.y;
    const float ma = __uint_as_float(ra0.z), mb = __uint_as_float(rb0.z);
    float xa[6] = {b2f_lo(ra0.w), b2f_hi(ra0.w), b2f_lo(ra1.x), b2f_hi(ra1.x),
                   b2f_lo(ra1.y), b2f_hi(ra1.y)};
    float xb[6] = {b2f_lo(rb0.w), b2f_hi(rb0.w), b2f_lo(rb1.x), b2f_hi(rb1.x),
                   b2f_lo(rb1.y), b2f_hi(rb1.y)};
    // U gathers only (V in registers)
    uint2 ua = *(const uint2*)(UV + ((size_t)(u32)sa << 9) + c0);
    uint2 ub = *(const uint2*)(UV + ((size_t)(u32)sb << 9) + c0);

    f32x2 yaA = (f32x2){b2f_lo(ua.x), b2f_hi(ua.x)} + vA;
    f32x2 yaB = (f32x2){b2f_lo(ua.y), b2f_hi(ua.y)} + vB;
    f32x2 ybA = (f32x2){b2f_lo(ub.x), b2f_hi(ub.x)} + vA;
    f32x2 ybB = (f32x2){b2f_lo(ub.y), b2f_hi(ub.y)} + vB;
#pragma unroll
    for (int k = 0; k < 6; k++) {
      yaA += xa[k] * wefA[k];
      yaB += xa[k] * wefB[k];
      ybA += xb[k] * wefA[k];
      ybB += xb[k] * wefB[k];
    }
    // sum of squares — original scalar association
    float pqa = yaA.x * yaA.x;
    pqa += yaA.y * yaA.y; pqa += yaB.x * yaB.x; pqa += yaB.y * yaB.y;
    float pqb = ybA.x * ybA.x;
    pqb += ybA.y * ybA.y; pqb += ybB.x * ybB.x; pqb += ybB.y * ybB.y;
    pqa += __shfl_xor(pqa, 32, 64);
    pqb += __shfl_xor(pqb, 32, 64);
    float z = (lane < 32) ? pqa : pqb;
#pragma unroll
    for (int m = 16; m >= 1; m >>= 1) z += __shfl_xor(z, m, 64);
    float zz = __shfl_xor(z, 32, 64);
    float pqa_t = (lane < 32) ? z : zz;
    float pqb_t = (lane < 32) ? zz : z;
    float rsa = rsqrtf(fmaxf(pqa_t * (1.f / 256.f) - ma * ma, 0.f) + 1e-5f);
    float rsb = rsqrtf(fmaxf(pqb_t * (1.f / 256.f) - mb * mb, 0.f) + 1e-5f);
    // LN + relu, packed (elementwise ops identical to scalar version)
    f32x2 nAa = __builtin_elementwise_max((yaA - ma) * rsa * glA + blA, zero2);
    f32x2 nAb = __builtin_elementwise_max((yaB - ma) * rsa * glB + blB, zero2);
    f32x2 nBa = __builtin_elementwise_max((ybA - mb) * rsb * glA + blA, zero2);
    f32x2 nBb = __builtin_elementwise_max((ybB - mb) * rsb * glB + blB, zero2);
    // final 2-wide matvec — original scalar association
    float p0a = nAa.x * w20[0], p1a = nAa.x * w21[0];
    p0a += nAa.y * w20[1]; p1a += nAa.y * w21[1];
    p0a += nAb.x * w20[2]; p1a += nAb.x * w21[2];
    p0a += nAb.y * w20[3]; p1a += nAb.y * w21[3];
    float p0b = nBa.x * w20[0], p1b = nBa.x * w21[0];
    p0b += nBa.y * w20[1]; p1b += nBa.y * w21[1];
    p0b += nBb.x * w20[2]; p1b += nBb.x * w21[2];
    p0b += nBb.y * w20[3]; p1b += nBb.y * w21[3];
    p0a += __shfl_xor(p0a, 32, 64); p1a += __shfl_xor(p1a, 32, 64);
    p0b += __shfl_xor(p0b, 32, 64); p1b += __shfl_xor(p1b, 32, 64);
    p0a += __shfl_xor(p0a, 16, 64); p1a += __shfl_xor(p1a, 16, 64);
    p0b += __shfl_xor(p0b, 16, 64); p1b += __shfl_xor(p1b, 16, 64);
    float w = (grp & 2) ? ((grp & 1) ? p1b : p0b) : ((grp & 1) ? p1a : p0a);
#pragma unroll
    for (int m = 8; m >= 1; m >>= 1) w += __shfl_xor(w, m, 64);
    if ((lane & 15) == 0) {
      float val = w + bsel;
      if (grp & 2) {
        if (two) {
          size_t oi = (size_t)eb * 2 + (grp & 1);
          if (usef) outEf[oi] = val; else outE[oi] = f2b(val);
        }
      } else {
        size_t oi = (size_t)ea * 2 + (grp & 1);
        if (usef) outEf[oi] = val; else outE[oi] = f2b(val);
      }
    }
  }
}

extern "C" void kernel_launch(void* const* d_in, const int* in_sizes, int n_in,
                              void* d_out, int out_size, void* d_ws, size_t ws_size,
                              hipStream_t stream) {
  char* wp = (char*)d_ws;
  auto alloc = [&](size_t bytes) -> char* {
    char* p = wp; wp += (bytes + 255) & ~(size_t)255; return p;
  };
  int* flag       = (int*)alloc(256);
  u16* c_h        = (u16*)alloc((size_t)N_NODES * 128 * 2);
  u16* c_ef       = (u16*)alloc((size_t)N_EDGES * 6 * 2);
  static const int pidx[20] = {4,5,6,7,8, 9,10,11,12, 13,14,15,16,17,18, 19,20,21,22,23};
  static const int pn[20]   = {16384,128,32768,256,32768, 1280,5,5,5,
                               135168,256,256,256,512,2, 65536,256,32768,128,32768};
  u16* cp[20];
  for (int a = 0; a < 20; a++) cp[a] = (u16*)alloc((size_t)pn[a] * 2);

  u16* wt_encpool = (u16*)alloc(128 * 128 * 2);
  u16* wt_enc     = (u16*)alloc(256 * 256 * 2);
  u16* wt_decpool = (u16*)alloc(256 * 256 * 2);
  u16* wt_dec     = (u16*)alloc(128 * 512 * 2);
  u16* wt_UV      = (u16*)alloc(512 * 288 * 2);
  u16* b512       = (u16*)alloc(512 * 2);
  float2* Srow    = (float2*)alloc((size_t)N_NODES * 8);
  float* swsum_b  = (float*)alloc(64);
  u16* m_buf      = (u16*)alloc((size_t)N_NODES * 256 * 2);
  u16* aggb       = (u16*)alloc((size_t)N_NODES * 256 * 2);
  u16* UVbuf      = m_buf;  // m_buf+aggb contiguous => [N][512] during edge phase
  u16* h1b        = (u16*)alloc((size_t)N_NODES * 256 * 2);
  u16* smb32      = (u16*)alloc((size_t)N_NODES * 32 * 2);
  int* deg        = (int*)alloc((size_t)N_NODES * 4);
  int* off        = (int*)alloc((size_t)(N_NODES + 1) * 4);
  int* cursor     = (int*)alloc((size_t)N_NODES * 4);
  int* esrc       = (int*)alloc((size_t)N_EDGES * 4);
  int* epos       = (int*)alloc((size_t)N_EDGES * 4);
  uint4* recs     = (uint4*)alloc(((size_t)N_EDGES * 2 + 8) * 16);  // 32B/edge, CSR order

  const int* src = (const int*)d_in[2];
  const int* dst = (const int*)d_in[3];

  u16* outN = (u16*)d_out;
  u16* outE = outN + (size_t)N_NODES * 5;
  u16* outH = outN + 1110000;
  float* outNf = (float*)d_out;
  float* outEf = outNf + (size_t)N_NODES * 5;
  float* outHf = outNf + 1110000;

  // --- init (deg zero + dtype sniff) ---
  init_sniff_deg<<<118, 256, 0, stream>>>((const u16*)d_in[0], flag, deg);
  // --- fused front-end: deg_count + all conversions ---
  ConvTab tab;
  int off_a = 0;
  for (int a = 0; a < 20; a++) {
    tab.e[a].s = d_in[pidx[a]]; tab.e[a].d = cp[a]; tab.e[a].n = pn[a]; tab.e[a].off = off_a;
    off_a += pn[a];
  }
  tab.total = off_a;
  int conv_blocks = 1875 + 3750 + 2813 + (off_a + 255) / 256;
  conv_all<<<conv_blocks, 256, 0, stream>>>(dst, deg, d_in[0], c_h, d_in[1], c_ef, tab, flag);

  const u16 *enc_Wpool = cp[0], *enc_bpool = cp[1], *enc_Wself = cp[2], *enc_bself = cp[3],
            *enc_Wneigh = cp[4], *np_W = cp[5], *np_b = cp[6], *np_g = cp[7], *np_beta = cp[8],
            *ep_W1 = cp[9], *ep_b1 = cp[10], *ep_g = cp[11], *ep_beta = cp[12],
            *ep_W2 = cp[13], *ep_b2 = cp[14], *dec_Wpool = cp[15], *dec_bpool = cp[16],
            *dec_Wself = cp[17], *dec_bself = cp[18], *dec_Wneigh = cp[19];

  // --- CSR build ---
  scan_off<<<1, 1024, 0, stream>>>(deg, off, cursor, N_NODES);
  fill_csr<<<1875, 256, 0, stream>>>(src, dst, cursor, esrc, epos, N_EDGES);

  // --- fused weight prep ---
  prep_weights<<<1347, 256, 0, stream>>>(enc_Wpool, enc_Wself, enc_Wneigh,
                                         dec_Wpool, dec_Wself, dec_Wneigh,
                                         ep_W1, ep_b1,
                                         wt_encpool, wt_enc, wt_decpool, wt_dec,
                                         wt_UV, b512, swsum_b);

  // --- encoder ---
  gemm_mfma<<<dim3(235, 1), 256, 0, stream>>>(c_h, nullptr, 128, 0, wt_encpool,
                                              enc_bpool, 1, m_buf, nullptr, flag, N_NODES, 128);
  agg128<<<1875, 256, 0, stream>>>(m_buf, esrc, off, aggb);
  gemm_mfma<<<dim3(235, 2), 256, 0, stream>>>(c_h, aggb, 128, 128, wt_enc,
                                              enc_bself, 1, h1b, nullptr, flag, N_NODES, 256);
  // --- node head ---
  node_head<<<118, 256, 0, stream>>>(h1b, np_W, np_b, np_g, np_beta, outN, outNf, flag, smb32);
  // --- edge head: UV GEMM -> row sums -> CSR edge records -> node-centric pointwise ---
  gemm_mfma<<<dim3(235, 4), 256, 0, stream>>>(h1b, smb32, 256, 32, wt_UV,
                                              b512, 0, UVbuf, nullptr, flag, N_NODES, 512);
  rowsum_uv<<<7500, 256, 0, stream>>>(UVbuf, Srow);
  edge_mean<<<1875, 256, 0, stream>>>(src, dst, c_ef, Srow, swsum_b, epos, recs);
  edge_pt<<<7500, 256, 0, stream>>>(UVbuf, recs, off, ep_W1, ep_g, ep_beta, ep_W2, ep_b2,
                                    outE, outEf, flag);
  // --- decoder ---
  gemm_mfma<<<dim3(235, 2), 256, 0, stream>>>(h1b, nullptr, 256, 0, wt_decpool,
                                              dec_bpool, 1, m_buf, nullptr, flag, N_NODES, 256);
  agg256<<<3750, 256, 0, stream>>>(m_buf, esrc, off, aggb);
  gemm_mfma<<<dim3(235, 1), 256, 0, stream>>>(h1b, aggb, 256, 256, wt_dec,
                                              dec_bself, 1, outH, outHf, flag, N_NODES, 128);
}

// Round 8
// 471.220 us; speedup vs baseline: 1.0558x; 1.0127x over previous
//
#include <hip/hip_runtime.h>

typedef unsigned short u16;
typedef unsigned int u32;
typedef __bf16 bf16_t;
typedef bf16_t bf16x8 __attribute__((ext_vector_type(8)));
typedef float f32x4 __attribute__((ext_vector_type(4)));
typedef float f32x2 __attribute__((ext_vector_type(2)));

#define N_NODES 30000
#define N_EDGES 480000

static __device__ __forceinline__ float b2f(u16 u) {
  return __uint_as_float(((u32)u) << 16);
}
static __device__ __forceinline__ float b2f_lo(u32 w) {
  return __uint_as_float(w << 16);
}
static __device__ __forceinline__ float b2f_hi(u32 w) {
  return __uint_as_float(w & 0xffff0000u);
}
static __device__ __forceinline__ u16 f2b(float f) {
  u32 x = __float_as_uint(f);
  u32 r = (x + 0x7fffu + ((x >> 16) & 1u)) >> 16;
  return (u16)r;
}

// ---------------- init: zero deg; block 0 sniffs dtype (bf16=0 / f32=1) ----------------
__global__ __launch_bounds__(256) void init_sniff_deg(const u16* __restrict__ h,
                                                      int* __restrict__ flag,
                                                      int* __restrict__ deg) {
  int i = blockIdx.x * 256 + threadIdx.x;
  if (i < N_NODES) deg[i] = 0;
  if (blockIdx.x == 0) {
    int t = threadIdx.x;
    int bad = 0;
#pragma unroll
    for (int j = 0; j < 4; j++) {
      u32 e = ((u32)h[t * 4 + j] >> 7) & 0xFFu;
      if (e >= 0x8Eu) bad = 1;  // impossible magnitude for N(0,1) bf16 data
    }
    int r = __syncthreads_or(bad);
    if (t == 0) *flag = r ? 1 : 0;
  }
}

struct ConvDesc { const void* s; u16* d; int n; int off; };
struct ConvTab { ConvDesc e[20]; int total; };

// ---------------- fused front-end: deg_count | conv h | conv ef | conv params ----------------
__global__ __launch_bounds__(256) void conv_all(
    const int* __restrict__ dstE, int* __restrict__ deg,
    const void* __restrict__ hsrc, u16* __restrict__ c_h,
    const void* __restrict__ efsrc, u16* __restrict__ c_ef,
    ConvTab tab, const int* __restrict__ flag) {
  int b = blockIdx.x;
  const int t = threadIdx.x;
  if (b < 1875) {
    int e = b * 256 + t;
    if (e < N_EDGES) atomicAdd(&deg[dstE[e]], 1);
    return;
  }
  b -= 1875;
  const int f = *flag;
  if (b < 3750) {  // h: 960000 uint2-groups
    int i = b * 256 + t;
    if (f) {
      float4 v = ((const float4*)hsrc)[i];
      uint2 o;
      o.x = (u32)f2b(v.x) | ((u32)f2b(v.y) << 16);
      o.y = (u32)f2b(v.z) | ((u32)f2b(v.w) << 16);
      ((uint2*)c_h)[i] = o;
    } else {
      ((uint2*)c_h)[i] = ((const uint2*)hsrc)[i];
    }
    return;
  }
  b -= 3750;
  if (b < 2813) {  // ef: 720000 4-elem groups
    int i = b * 256 + t;
    if (i < 720000) {
      if (f) {
        float4 v = ((const float4*)efsrc)[i];
        uint2 o;
        o.x = (u32)f2b(v.x) | ((u32)f2b(v.y) << 16);
        o.y = (u32)f2b(v.z) | ((u32)f2b(v.w) << 16);
        ((uint2*)c_ef)[i] = o;
      } else {
        ((uint2*)c_ef)[i] = ((const uint2*)efsrc)[i];
      }
    }
    return;
  }
  b -= 2813;
  int i = b * 256 + t;
  if (i >= tab.total) return;
#pragma unroll 1
  for (int a = 0; a < 20; a++) {
    int j = i - tab.e[a].off;
    if (j >= 0 && j < tab.e[a].n) {
      if (f) tab.e[a].d[j] = f2b(((const float*)tab.e[a].s)[j]);
      else tab.e[a].d[j] = ((const u16*)tab.e[a].s)[j];
      return;
    }
  }
}

__global__ __launch_bounds__(1024) void scan_off(const int* __restrict__ deg,
                                                 int* __restrict__ off,
                                                 int* __restrict__ cursor, int n) {
  __shared__ int carry;
  __shared__ int wsum[16];
  int t = threadIdx.x, lane = t & 63, wv = t >> 6;
  if (t == 0) { carry = 0; off[0] = 0; }
  __syncthreads();
  for (int base = 0; base < n; base += 1024) {
    int v = (base + t < n) ? deg[base + t] : 0;
    int x = v;
#pragma unroll
    for (int d = 1; d < 64; d <<= 1) {
      int y = __shfl_up(x, d, 64);
      if (lane >= d) x += y;
    }
    if (lane == 63) wsum[wv] = x;
    __syncthreads();
    int wadd = 0;
    for (int w = 0; w < wv; w++) wadd += wsum[w];
    int incl = x + wadd + carry;
    if (base + t < n) { off[base + t + 1] = incl; cursor[base + t] = incl - v; }
    __syncthreads();
    if (t == 1023) carry = incl;
    __syncthreads();
  }
}

// fill_csr + epos: epos[e] = CSR slot of original edge e (for CSR-ordered edge records)
__global__ __launch_bounds__(256) void fill_csr(const int* __restrict__ src,
                                                const int* __restrict__ dst,
                                                int* __restrict__ cursor,
                                                int* __restrict__ esrc,
                                                int* __restrict__ epos, int nE) {
  int e = blockIdx.x * 256 + threadIdx.x;
  if (e >= nE) return;
  int p = atomicAdd(&cursor[dst[e]], 1);
  esrc[p] = src[e];
  epos[e] = p;
}

#define MRG(r)                                                    \
  do {                                                            \
    a0 = max(a0, (r).x & 0xffffu); a1 = max(a1, (r).x >> 16);     \
    a2 = max(a2, (r).y & 0xffffu); a3 = max(a3, (r).y >> 16);     \
    a4 = max(a4, (r).z & 0xffffu); a5 = max(a5, (r).z >> 16);     \
    a6 = max(a6, (r).w & 0xffffu); a7 = max(a7, (r).w >> 16);     \
  } while (0)

// ---------------- CSR max-aggregate (unsigned max == float max for bf16 >= 0) ----------------
// 4 nodes per wave; 16 lanes x uint4 per row (128 cols).
__global__ __launch_bounds__(256) void agg128(const u16* __restrict__ m,
                                              const int* __restrict__ esrc,
                                              const int* __restrict__ off,
                                              u16* __restrict__ out) {
  int wv = threadIdx.x >> 6, lane = threadIdx.x & 63;
  int qd = lane >> 4, l = lane & 15;
  int n = blockIdx.x * 16 + wv * 4 + qd;
  if (n >= N_NODES) return;
  int i = off[n], s1 = off[n + 1];
  u32 a0 = 0, a1 = 0, a2 = 0, a3 = 0, a4 = 0, a5 = 0, a6 = 0, a7 = 0;
  for (; i + 1 < s1; i += 2) {
    int e0 = esrc[i], e1 = esrc[i + 1];
    uint4 r0 = *(const uint4*)(m + (size_t)e0 * 128 + l * 8);
    uint4 r1 = *(const uint4*)(m + (size_t)e1 * 128 + l * 8);
    MRG(r0); MRG(r1);
  }
  if (i < s1) {
    uint4 r0 = *(const uint4*)(m + (size_t)esrc[i] * 128 + l * 8);
    MRG(r0);
  }
  uint4 w;
  w.x = a0 | (a1 << 16); w.y = a2 | (a3 << 16);
  w.z = a4 | (a5 << 16); w.w = a6 | (a7 << 16);
  *(uint4*)(out + (size_t)n * 128 + l * 8) = w;
}

// 2 nodes per wave; 32 lanes x uint4 per row (256 cols).
__global__ __launch_bounds__(256) void agg256(const u16* __restrict__ m,
                                              const int* __restrict__ esrc,
                                              const int* __restrict__ off,
                                              u16* __restrict__ out) {
  int wv = threadIdx.x >> 6, lane = threadIdx.x & 63;
  int half = lane >> 5, l = lane & 31;
  int n = blockIdx.x * 8 + wv * 2 + half;
  if (n >= N_NODES) return;
  int i = off[n], s1 = off[n + 1];
  u32 a0 = 0, a1 = 0, a2 = 0, a3 = 0, a4 = 0, a5 = 0, a6 = 0, a7 = 0;
  for (; i + 1 < s1; i += 2) {
    int e0 = esrc[i], e1 = esrc[i + 1];
    uint4 r0 = *(const uint4*)(m + (size_t)e0 * 256 + l * 8);
    uint4 r1 = *(const uint4*)(m + (size_t)e1 * 256 + l * 8);
    MRG(r0); MRG(r1);
  }
  if (i < s1) {
    uint4 r0 = *(const uint4*)(m + (size_t)esrc[i] * 256 + l * 8);
    MRG(r0);
  }
  uint4 w;
  w.x = a0 | (a1 << 16); w.y = a2 | (a3 << 16);
  w.z = a4 | (a5 << 16); w.w = a6 | (a7 << 16);
  *(uint4*)(out + (size_t)n * 256 + l * 8) = w;
}
#undef MRG

// ---------------- fused weight prep: all transposes + UV build + b512 + wefsum ----------------
__global__ __launch_bounds__(256) void prep_weights(
    const u16* __restrict__ encWp, const u16* __restrict__ encWs, const u16* __restrict__ encWn,
    const u16* __restrict__ decWp, const u16* __restrict__ decWs, const u16* __restrict__ decWn,
    const u16* __restrict__ epW1, const u16* __restrict__ epb1,
    u16* __restrict__ wt_encpool, u16* __restrict__ wt_enc,
    u16* __restrict__ wt_decpool, u16* __restrict__ wt_dec,
    u16* __restrict__ wt_UV, u16* __restrict__ b512, float* __restrict__ swsum) {
  int b = blockIdx.x;
  const int t = threadIdx.x;
  if (b < 64) {
    int idx = b * 256 + t; int k = idx >> 7, n = idx & 127;
    wt_encpool[n * 128 + k] = encWp[k * 128 + n]; return;
  }
  b -= 64;
  if (b < 128) {
    int idx = b * 256 + t; int k = idx >> 8, n = idx & 255;
    wt_enc[n * 256 + k] = encWs[k * 256 + n]; return;
  }
  b -= 128;
  if (b < 128) {
    int idx = b * 256 + t; int k = idx >> 8, n = idx & 255;
    wt_enc[n * 256 + 128 + k] = encWn[k * 256 + n]; return;
  }
  b -= 128;
  if (b < 256) {
    int idx = b * 256 + t; int k = idx >> 8, n = idx & 255;
    wt_decpool[n * 256 + k] = decWp[k * 256 + n]; return;
  }
  b -= 256;
  if (b < 128) {
    int idx = b * 256 + t; int k = idx >> 7, n = idx & 127;
    wt_dec[n * 512 + k] = decWs[k * 128 + n]; return;
  }
  b -= 128;
  if (b < 128) {
    int idx = b * 256 + t; int k = idx >> 7, n = idx & 127;
    wt_dec[n * 512 + 256 + k] = decWn[k * 128 + n]; return;
  }
  b -= 128;
  if (b < 512) {
    int n = b, n2 = n & 255, base = (n >= 256) ? 267 : 0;
    for (int kp = t; kp < 288; kp += 256) {
      u16 v = (kp < 261) ? epW1[(size_t)(base + kp) * 256 + n2] : (u16)0;
      wt_UV[(size_t)n * 288 + kp] = v;
    }
    return;
  }
  b -= 512;
  if (b < 2) {
    int i = b * 256 + t;
    b512[i] = (i < 256) ? epb1[i] : (u16)0; return;
  }
  int k = t >> 5, l32 = t & 31;
  if (k < 6) {
    uint4 v = *(const uint4*)(epW1 + (size_t)(261 + k) * 256 + l32 * 8);
    float s = b2f_lo(v.x) + b2f_hi(v.x) + b2f_lo(v.y) + b2f_hi(v.y) +
              b2f_lo(v.z) + b2f_hi(v.z) + b2f_lo(v.w) + b2f_hi(v.w);
#pragma unroll
    for (int m = 1; m < 32; m <<= 1) s += __shfl_xor(s, m, 64);
    if (l32 == 0) swsum[k] = s;
  }
}

// ---------------- generic MFMA GEMM: C = act(concat(A0,A1) @ Bt^T + bias) ----------------
__global__ __launch_bounds__(256) void gemm_mfma(
    const u16* __restrict__ A0, const u16* __restrict__ A1, int K0, int K1,
    const u16* __restrict__ Bt, const u16* __restrict__ bias, int do_relu,
    u16* __restrict__ C, float* __restrict__ Cf, const int* __restrict__ flag,
    int M, int Nld) {
  __shared__ __align__(16) u16 As[128 * 40];
  __shared__ __align__(16) u16 Bs[128 * 40];
  const int t = threadIdx.x;
  const int lane = t & 63, wv = t >> 6;
  const int wm = wv & 1, wn = wv >> 1;
  const int r = lane & 15, q = lane >> 4;
  const int bm = blockIdx.x, bn = blockIdx.y;
  const int Ktot = K0 + K1;
  const bool usef = (Cf != nullptr) && (*flag != 0);

  f32x4 acc[4][4];
#pragma unroll
  for (int i = 0; i < 4; i++)
#pragma unroll
    for (int j = 0; j < 4; j++) acc[i][j] = (f32x4){0.f, 0.f, 0.f, 0.f};

  for (int kc = 0; kc < Ktot; kc += 32) {
#pragma unroll
    for (int h = 0; h < 2; h++) {
      int idx = t + h * 256;          // 0..511
      int rr = idx >> 2, qq = idx & 3;
      int rowg = bm * 128 + rr;
      uint4 av = make_uint4(0, 0, 0, 0);
      if (rowg < M) {
        const u16* p = (kc < K0) ? (A0 + (size_t)rowg * K0 + kc)
                                 : (A1 + (size_t)rowg * K1 + (kc - K0));
        av = *(const uint4*)(p + qq * 8);
      }
      *(uint4*)&As[rr * 40 + qq * 8] = av;
      int ng = bn * 128 + rr;
      uint4 bv = *(const uint4*)(Bt + (size_t)ng * Ktot + kc + qq * 8);
      *(uint4*)&Bs[rr * 40 + qq * 8] = bv;
    }
    __syncthreads();
    bf16x8 af[4], bfm[4];
#pragma unroll
    for (int mi = 0; mi < 4; mi++)
      af[mi] = *(const bf16x8*)&As[(wm * 64 + mi * 16 + r) * 40 + q * 8];
#pragma unroll
    for (int ni = 0; ni < 4; ni++)
      bfm[ni] = *(const bf16x8*)&Bs[(wn * 64 + ni * 16 + r) * 40 + q * 8];
#pragma unroll
    for (int mi = 0; mi < 4; mi++)
#pragma unroll
      for (int ni = 0; ni < 4; ni++)
        acc[mi][ni] = __builtin_amdgcn_mfma_f32_16x16x32_bf16(af[mi], bfm[ni], acc[mi][ni], 0, 0, 0);
    __syncthreads();
  }

  float bv[4];
#pragma unroll
  for (int ni = 0; ni < 4; ni++)
    bv[ni] = bias ? b2f(bias[bn * 128 + wn * 64 + ni * 16 + r]) : 0.f;
#pragma unroll
  for (int mi = 0; mi < 4; mi++) {
#pragma unroll
    for (int i = 0; i < 4; i++) {
      int rowg = bm * 128 + wm * 64 + mi * 16 + q * 4 + i;
      if (rowg >= M) continue;
#pragma unroll
      for (int ni = 0; ni < 4; ni++) {
        int colg = bn * 128 + wn * 64 + ni * 16 + r;
        float v = acc[mi][ni][i] + bv[ni];
        if (do_relu) v = v > 0.f ? v : 0.f;
        if (usef) Cf[(size_t)rowg * Nld + colg] = v;
        else C[(size_t)rowg * Nld + colg] = f2b(v);
      }
    }
  }
}

// ---------------- node head: node_pred = LN(h1@W + b), smb32 = [softmax | 0-pad] ----------------
__global__ __launch_bounds__(256) void node_head(
    const u16* __restrict__ h1, const u16* __restrict__ W, const u16* __restrict__ b,
    const u16* __restrict__ g, const u16* __restrict__ beta,
    u16* __restrict__ outN, float* __restrict__ outNf, const int* __restrict__ flag,
    u16* __restrict__ smOut) {
  __shared__ float Wl[256 * 5];
  __shared__ float bl[5], gl[5], betal[5];
  int t = threadIdx.x;
#pragma unroll
  for (int c = 0; c < 5; c++) Wl[t * 5 + c] = b2f(W[t * 5 + c]);
  if (t < 5) { bl[t] = b2f(b[t]); gl[t] = b2f(g[t]); betal[t] = b2f(beta[t]); }
  __syncthreads();
  int n = blockIdx.x * 256 + t;
  if (n >= N_NODES) return;
  const bool usef = (*flag != 0);
  float acc[5] = {0.f, 0.f, 0.f, 0.f, 0.f};
  const u16* hp = h1 + (size_t)n * 256;
  for (int k8 = 0; k8 < 32; k8++) {
    uint4 v = *(const uint4*)(hp + k8 * 8);
    u32 wds[4] = {v.x, v.y, v.z, v.w};
#pragma unroll
    for (int h = 0; h < 4; h++) {
      float x0 = b2f_lo(wds[h]), x1 = b2f_hi(wds[h]);
      int k = k8 * 8 + h * 2;
#pragma unroll
      for (int c = 0; c < 5; c++)
        acc[c] += x0 * Wl[k * 5 + c] + x1 * Wl[(k + 1) * 5 + c];
    }
  }
  float x[5], mu = 0.f;
#pragma unroll
  for (int c = 0; c < 5; c++) { x[c] = acc[c] + bl[c]; mu += x[c]; }
  mu *= 0.2f;
  float var = 0.f;
#pragma unroll
  for (int c = 0; c < 5; c++) { float d = x[c] - mu; var += d * d; }
  var *= 0.2f;
  float rstd = rsqrtf(fmaxf(var, 0.f) + 1e-5f);
  float v5[5], mx = -1e30f;
#pragma unroll
  for (int c = 0; c < 5; c++) {
    v5[c] = gl[c] * (x[c] - mu) * rstd + betal[c];
    if (usef) outNf[(size_t)n * 5 + c] = v5[c];
    else outN[(size_t)n * 5 + c] = f2b(v5[c]);
    mx = fmaxf(mx, v5[c]);
  }
  float s = 0.f, ex[5];
#pragma unroll
  for (int c = 0; c < 5; c++) { ex[c] = __expf(v5[c] - mx); s += ex[c]; }
  float inv = 1.f / s;
  u16 row[32];
#pragma unroll
  for (int c = 0; c < 5; c++) row[c] = f2b(ex[c] * inv);
#pragma unroll
  for (int c = 5; c < 32; c++) row[c] = 0;
#pragma unroll
  for (int c = 0; c < 4; c++)
    *(uint4*)(smOut + (size_t)n * 32 + c * 8) = *(const uint4*)&row[c * 8];
}

// ---------------- row sums of UV ----------------
__global__ __launch_bounds__(256) void rowsum_uv(const u16* __restrict__ UV,
                                                 float2* __restrict__ Srow) {
  int wv = threadIdx.x >> 6, lane = threadIdx.x & 63;
  int n = blockIdx.x * 4 + wv;
  if (n >= N_NODES) return;
  uint4 v = *(const uint4*)(UV + (size_t)n * 512 + lane * 8);
  float s = b2f_lo(v.x) + b2f_hi(v.x) + b2f_lo(v.y) + b2f_hi(v.y) +
            b2f_lo(v.z) + b2f_hi(v.z) + b2f_lo(v.w) + b2f_hi(v.w);
#pragma unroll
  for (int m = 1; m < 32; m <<= 1) s += __shfl_xor(s, m, 64);
  if (lane == 0) Srow[n].x = s;    // U half (lanes 0-31)
  if (lane == 32) Srow[n].y = s;   // V half (lanes 32-63)
}

// ---------------- per-edge records in CSR (dst-grouped) order, 32B each ----------------
// record: r0 = {src, orig_e, m, ef0} ; r1 = {ef1, ef2, dst, 0}. Written at slot epos[e].
// Slots [N_EDGES, N_EDGES+32) zero-filled for the edge_pt record prefetch.
__global__ __launch_bounds__(256) void edge_mean(
    const int* __restrict__ src, const int* __restrict__ dst,
    const u16* __restrict__ ef, const float2* __restrict__ Srow,
    const float* __restrict__ swsum, const int* __restrict__ epos,
    uint4* __restrict__ recs) {
  int e = blockIdx.x * 256 + threadIdx.x;
  if (e >= N_EDGES) {
    if (e < N_EDGES + 32) {
      uint4 z = make_uint4(0, 0, 0, 0);
      recs[(size_t)e * 2 + 0] = z;
      recs[(size_t)e * 2 + 1] = z;
    }
    return;
  }
  int s0 = src[e], d0 = dst[e];
  const u32* efp = (const u32*)(ef + (size_t)e * 6);
  u32 f0 = efp[0], f1 = efp[1], f2 = efp[2];
  float xa[6] = {b2f_lo(f0), b2f_hi(f0), b2f_lo(f1), b2f_hi(f1), b2f_lo(f2), b2f_hi(f2)};
  float sw[6];
#pragma unroll
  for (int k = 0; k < 6; k++) sw[k] = swsum[k];
  float m0 = Srow[s0].x + Srow[d0].y;
#pragma unroll
  for (int k = 0; k < 6; k++) m0 += xa[k] * sw[k];
  m0 *= (1.f / 256.f);
  int p = epos[e];
  uint4 r0, r1;
  r0.x = (u32)s0; r0.y = (u32)e; r0.z = __float_as_uint(m0); r0.w = f0;
  r1.x = f1; r1.y = f2; r1.z = (u32)d0; r1.w = 0;
  recs[(size_t)p * 2 + 0] = r0;
  recs[(size_t)p * 2 + 1] = r1;
}

// ---------------- edge pointwise v7: v4 uniform structure over CSR-ORDERED edges ----------------
// 16 pairs of consecutive CSR slots per wave (fixed trip count, perfectly balanced).
// Consecutive slots share dst (avg degree 16) -> V[dst] gathers hit L1/L2, halving the
// random-gather bytes. Per-edge FP op order identical to v4; reduction tree computes
// per-edge sums independently -> bit-identical for any edge ordering.
__global__ __launch_bounds__(256) void edge_pt(
    const u16* __restrict__ UV, const uint4* __restrict__ recs,
    const u16* __restrict__ w1raw,
    const u16* __restrict__ g, const u16* __restrict__ beta,
    const u16* __restrict__ w2, const u16* __restrict__ b2,
    u16* __restrict__ outE, float* __restrict__ outEf, const int* __restrict__ flag) {
  const int t = threadIdx.x;
  const int lane = t & 63, wv = t >> 6;
  const int c0 = lane * 4;
  const int grp = (lane >> 4) & 3;  // 16-lane group id
  f32x2 wefA[6], wefB[6];           // ef->W1 rows, cols {c0,c0+1} / {c0+2,c0+3}
#pragma unroll
  for (int k = 0; k < 6; k++) {
    u32 wa = *(const u32*)(w1raw + (size_t)(261 + k) * 256 + c0);
    u32 wb = *(const u32*)(w1raw + (size_t)(261 + k) * 256 + c0 + 2);
    wefA[k] = (f32x2){b2f_lo(wa), b2f_hi(wa)};
    wefB[k] = (f32x2){b2f_lo(wb), b2f_hi(wb)};
  }
  f32x2 glA = (f32x2){b2f(g[c0]), b2f(g[c0 + 1])};
  f32x2 glB = (f32x2){b2f(g[c0 + 2]), b2f(g[c0 + 3])};
  f32x2 blA = (f32x2){b2f(beta[c0]), b2f(beta[c0 + 1])};
  f32x2 blB = (f32x2){b2f(beta[c0 + 2]), b2f(beta[c0 + 3])};
  float w20[4], w21[4];
#pragma unroll
  for (int j = 0; j < 4; j++) {
    w20[j] = b2f(w2[(c0 + j) * 2]); w21[j] = b2f(w2[(c0 + j) * 2 + 1]);
  }
  const float b20 = b2f(b2[0]), b21 = b2f(b2[1]);
  const float bsel = (grp & 1) ? b21 : b20;
  const bool usef = (*flag != 0);
  const f32x2 zero2 = (f32x2){0.f, 0.f};

  // CSR-slot pair base — force uniform so record loads become s_load
  const int pb = __builtin_amdgcn_readfirstlane((blockIdx.x * 4 + wv) * 16);
  const uint4* rp = recs + (size_t)pb * 4;  // 4 uint4 per pair (2 records)
  uint4 ra0 = rp[0], ra1 = rp[1], rb0 = rp[2], rb1 = rp[3];
#pragma unroll 1
  for (int it = 0; it < 16; ++it) {
    uint4 ca0 = ra0, ca1 = ra1, cb0 = rb0, cb1 = rb1;
    // prefetch next pair's records (tail over-read lands in zero-filled pad)
    ra0 = rp[4 * it + 4]; ra1 = rp[4 * it + 5];
    rb0 = rp[4 * it + 6]; rb1 = rp[4 * it + 7];
    const int sa = (int)ca0.x, ea = (int)ca0.y, da = (int)ca1.z;
    const int sb = (int)cb0.x, eb = (int)cb0.y, db = (int)cb1.z;
    const float ma = __uint_as_float(ca0.z), mb = __uint_as_float(cb0.z);
    float xa[6] = {b2f_lo(ca0.w), b2f_hi(ca0.w), b2f_lo(ca1.x), b2f_hi(ca1.x),
                   b2f_lo(ca1.y), b2f_hi(ca1.y)};
    float xb[6] = {b2f_lo(cb0.w), b2f_hi(cb0.w), b2f_lo(cb1.x), b2f_hi(cb1.x),
                   b2f_lo(cb1.y), b2f_hi(cb1.y)};
    // UV gathers: SGPR base + constant per-lane offset. da/db repeat across ~16
    // consecutive slots -> V gathers are cache hits.
    uint2 ua = *(const uint2*)(UV + ((size_t)(u32)sa << 9) + c0);
    uint2 va = *(const uint2*)(UV + ((size_t)(u32)da << 9) + 256 + c0);
    uint2 ub = *(const uint2*)(UV + ((size_t)(u32)sb << 9) + c0);
    uint2 vb = *(const uint2*)(UV + ((size_t)(u32)db << 9) + 256 + c0);

    f32x2 yaA = (f32x2){b2f_lo(ua.x), b2f_hi(ua.x)} + (f32x2){b2f_lo(va.x), b2f_hi(va.x)};
    f32x2 yaB = (f32x2){b2f_lo(ua.y), b2f_hi(ua.y)} + (f32x2){b2f_lo(va.y), b2f_hi(va.y)};
    f32x2 ybA = (f32x2){b2f_lo(ub.x), b2f_hi(ub.x)} + (f32x2){b2f_lo(vb.x), b2f_hi(vb.x)};
    f32x2 ybB = (f32x2){b2f_lo(ub.y), b2f_hi(ub.y)} + (f32x2){b2f_lo(vb.y), b2f_hi(vb.y)};
#pragma unroll
    for (int k = 0; k < 6; k++) {
      yaA += xa[k] * wefA[k];
      yaB += xa[k] * wefB[k];
      ybA += xb[k] * wefA[k];
      ybB += xb[k] * wefB[k];
    }
    // sum of squares — original scalar association
    float pqa = yaA.x * yaA.x;
    pqa += yaA.y * yaA.y; pqa += yaB.x * yaB.x; pqa += yaB.y * yaB.y;
    float pqb = ybA.x * ybA.x;
    pqb += ybA.y * ybA.y; pqb += ybB.x * ybB.x; pqb += ybB.y * ybB.y;
    pqa += __shfl_xor(pqa, 32, 64);
    pqb += __shfl_xor(pqb, 32, 64);
    float z = (lane < 32) ? pqa : pqb;
#pragma unroll
    for (int m = 16; m >= 1; m >>= 1) z += __shfl_xor(z, m, 64);
    float zz = __shfl_xor(z, 32, 64);
    float pqa_t = (lane < 32) ? z : zz;
    float pqb_t = (lane < 32) ? zz : z;
    float rsa = rsqrtf(fmaxf(pqa_t * (1.f / 256.f) - ma * ma, 0.f) + 1e-5f);
    float rsb = rsqrtf(fmaxf(pqb_t * (1.f / 256.f) - mb * mb, 0.f) + 1e-5f);
    // LN + relu, packed (elementwise ops identical to scalar version)
    f32x2 nAa = __builtin_elementwise_max((yaA - ma) * rsa * glA + blA, zero2);
    f32x2 nAb = __builtin_elementwise_max((yaB - ma) * rsa * glB + blB, zero2);
    f32x2 nBa = __builtin_elementwise_max((ybA - mb) * rsb * glA + blA, zero2);
    f32x2 nBb = __builtin_elementwise_max((ybB - mb) * rsb * glB + blB, zero2);
    // final 2-wide matvec — original scalar association
    float p0a = nAa.x * w20[0], p1a = nAa.x * w21[0];
    p0a += nAa.y * w20[1]; p1a += nAa.y * w21[1];
    p0a += nAb.x * w20[2]; p1a += nAb.x * w21[2];
    p0a += nAb.y * w20[3]; p1a += nAb.y * w21[3];
    float p0b = nBa.x * w20[0], p1b = nBa.x * w21[0];
    p0b += nBa.y * w20[1]; p1b += nBa.y * w21[1];
    p0b += nBb.x * w20[2]; p1b += nBb.x * w21[2];
    p0b += nBb.y * w20[3]; p1b += nBb.y * w21[3];
    p0a += __shfl_xor(p0a, 32, 64); p1a += __shfl_xor(p1a, 32, 64);
    p0b += __shfl_xor(p0b, 32, 64); p1b += __shfl_xor(p1b, 32, 64);
    p0a += __shfl_xor(p0a, 16, 64); p1a += __shfl_xor(p1a, 16, 64);
    p0b += __shfl_xor(p0b, 16, 64); p1b += __shfl_xor(p1b, 16, 64);
    float w = (grp & 2) ? ((grp & 1) ? p1b : p0b) : ((grp & 1) ? p1a : p0a);
#pragma unroll
    for (int m = 8; m >= 1; m >>= 1) w += __shfl_xor(w, m, 64);
    if ((lane & 15) == 0) {
      float val = w + bsel;
      size_t oi = (grp & 2) ? ((size_t)eb * 2 + (grp & 1)) : ((size_t)ea * 2 + (grp & 1));
      if (usef) outEf[oi] = val;
      else outE[oi] = f2b(val);
    }
  }
}

extern "C" void kernel_launch(void* const* d_in, const int* in_sizes, int n_in,
                              void* d_out, int out_size, void* d_ws, size_t ws_size,
                              hipStream_t stream) {
  char* wp = (char*)d_ws;
  auto alloc = [&](size_t bytes) -> char* {
    char* p = wp; wp += (bytes + 255) & ~(size_t)255; return p;
  };
  int* flag       = (int*)alloc(256);
  u16* c_h        = (u16*)alloc((size_t)N_NODES * 128 * 2);
  u16* c_ef       = (u16*)alloc((size_t)N_EDGES * 6 * 2);
  static const int pidx[20] = {4,5,6,7,8, 9,10,11,12, 13,14,15,16,17,18, 19,20,21,22,23};
  static const int pn[20]   = {16384,128,32768,256,32768, 1280,5,5,5,
                               135168,256,256,256,512,2, 65536,256,32768,128,32768};
  u16* cp[20];
  for (int a = 0; a < 20; a++) cp[a] = (u16*)alloc((size_t)pn[a] * 2);

  u16* wt_encpool = (u16*)alloc(128 * 128 * 2);
  u16* wt_enc     = (u16*)alloc(256 * 256 * 2);
  u16* wt_decpool = (u16*)alloc(256 * 256 * 2);
  u16* wt_dec     = (u16*)alloc(128 * 512 * 2);
  u16* wt_UV      = (u16*)alloc(512 * 288 * 2);
  u16* b512       = (u16*)alloc(512 * 2);
  float2* Srow    = (float2*)alloc((size_t)N_NODES * 8);
  float* swsum_b  = (float*)alloc(64);
  u16* m_buf      = (u16*)alloc((size_t)N_NODES * 256 * 2);
  u16* aggb       = (u16*)alloc((size_t)N_NODES * 256 * 2);
  u16* UVbuf      = m_buf;  // m_buf+aggb contiguous => [N][512] during edge phase
  u16* h1b        = (u16*)alloc((size_t)N_NODES * 256 * 2);
  u16* smb32      = (u16*)alloc((size_t)N_NODES * 32 * 2);
  int* deg        = (int*)alloc((size_t)N_NODES * 4);
  int* off        = (int*)alloc((size_t)(N_NODES + 1) * 4);
  int* cursor     = (int*)alloc((size_t)N_NODES * 4);
  int* esrc       = (int*)alloc((size_t)N_EDGES * 4);
  int* epos       = (int*)alloc((size_t)N_EDGES * 4);
  uint4* recs     = (uint4*)alloc(((size_t)(N_EDGES + 32) * 2) * 16);  // 32B/edge, CSR order

  const int* src = (const int*)d_in[2];
  const int* dst = (const int*)d_in[3];

  u16* outN = (u16*)d_out;
  u16* outE = outN + (size_t)N_NODES * 5;
  u16* outH = outN + 1110000;
  float* outNf = (float*)d_out;
  float* outEf = outNf + (size_t)N_NODES * 5;
  float* outHf = outNf + 1110000;

  // --- init (deg zero + dtype sniff) ---
  init_sniff_deg<<<118, 256, 0, stream>>>((const u16*)d_in[0], flag, deg);
  // --- fused front-end: deg_count + all conversions ---
  ConvTab tab;
  int off_a = 0;
  for (int a = 0; a < 20; a++) {
    tab.e[a].s = d_in[pidx[a]]; tab.e[a].d = cp[a]; tab.e[a].n = pn[a]; tab.e[a].off = off_a;
    off_a += pn[a];
  }
  tab.total = off_a;
  int conv_blocks = 1875 + 3750 + 2813 + (off_a + 255) / 256;
  conv_all<<<conv_blocks, 256, 0, stream>>>(dst, deg, d_in[0], c_h, d_in[1], c_ef, tab, flag);

  const u16 *enc_Wpool = cp[0], *enc_bpool = cp[1], *enc_Wself = cp[2], *enc_bself = cp[3],
            *enc_Wneigh = cp[4], *np_W = cp[5], *np_b = cp[6], *np_g = cp[7], *np_beta = cp[8],
            *ep_W1 = cp[9], *ep_b1 = cp[10], *ep_g = cp[11], *ep_beta = cp[12],
            *ep_W2 = cp[13], *ep_b2 = cp[14], *dec_Wpool = cp[15], *dec_bpool = cp[16],
            *dec_Wself = cp[17], *dec_bself = cp[18], *dec_Wneigh = cp[19];

  // --- CSR build ---
  scan_off<<<1, 1024, 0, stream>>>(deg, off, cursor, N_NODES);
  fill_csr<<<1875, 256, 0, stream>>>(src, dst, cursor, esrc, epos, N_EDGES);

  // --- fused weight prep ---
  prep_weights<<<1347, 256, 0, stream>>>(enc_Wpool, enc_Wself, enc_Wneigh,
                                         dec_Wpool, dec_Wself, dec_Wneigh,
                                         ep_W1, ep_b1,
                                         wt_encpool, wt_enc, wt_decpool, wt_dec,
                                         wt_UV, b512, swsum_b);

  // --- encoder ---
  gemm_mfma<<<dim3(235, 1), 256, 0, stream>>>(c_h, nullptr, 128, 0, wt_encpool,
                                              enc_bpool, 1, m_buf, nullptr, flag, N_NODES, 128);
  agg128<<<1875, 256, 0, stream>>>(m_buf, esrc, off, aggb);
  gemm_mfma<<<dim3(235, 2), 256, 0, stream>>>(c_h, aggb, 128, 128, wt_enc,
                                              enc_bself, 1, h1b, nullptr, flag, N_NODES, 256);
  // --- node head ---
  node_head<<<118, 256, 0, stream>>>(h1b, np_W, np_b, np_g, np_beta, outN, outNf, flag, smb32);
  // --- edge head: UV GEMM -> row sums -> CSR edge records -> uniform pointwise ---
  gemm_mfma<<<dim3(235, 4), 256, 0, stream>>>(h1b, smb32, 256, 32, wt_UV,
                                              b512, 0, UVbuf, nullptr, flag, N_NODES, 512);
  rowsum_uv<<<7500, 256, 0, stream>>>(UVbuf, Srow);
  edge_mean<<<1876, 256, 0, stream>>>(src, dst, c_ef, Srow, swsum_b, epos, recs);
  edge_pt<<<3750, 256, 0, stream>>>(UVbuf, recs, ep_W1, ep_g, ep_beta, ep_W2, ep_b2,
                                    outE, outEf, flag);
  // --- decoder ---
  gemm_mfma<<<dim3(235, 2), 256, 0, stream>>>(h1b, nullptr, 256, 0, wt_decpool,
                                              dec_bpool, 1, m_buf, nullptr, flag, N_NODES, 256);
  agg256<<<3750, 256, 0, stream>>>(m_buf, esrc, off, aggb);
  gemm_mfma<<<dim3(235, 1), 256, 0, stream>>>(h1b, aggb, 256, 256, wt_dec,
                                              dec_bself, 1, outH, outHf, flag, N_NODES, 128);
}

// Round 9
// 459.381 us; speedup vs baseline: 1.0830x; 1.0258x over previous
//
#include <hip/hip_runtime.h>

typedef unsigned short u16;
typedef unsigned int u32;
typedef __bf16 bf16_t;
typedef bf16_t bf16x8 __attribute__((ext_vector_type(8)));
typedef float f32x4 __attribute__((ext_vector_type(4)));
typedef float f32x2 __attribute__((ext_vector_type(2)));

#define N_NODES 30000
#define N_EDGES 480000

static __device__ __forceinline__ float b2f(u16 u) {
  return __uint_as_float(((u32)u) << 16);
}
static __device__ __forceinline__ float b2f_lo(u32 w) {
  return __uint_as_float(w << 16);
}
static __device__ __forceinline__ float b2f_hi(u32 w) {
  return __uint_as_float(w & 0xffff0000u);
}
static __device__ __forceinline__ u16 f2b(float f) {
  u32 x = __float_as_uint(f);
  u32 r = (x + 0x7fffu + ((x >> 16) & 1u)) >> 16;
  return (u16)r;
}

// ---------------- init: zero deg; block 0 sniffs dtype (bf16=0 / f32=1) ----------------
__global__ __launch_bounds__(256) void init_sniff_deg(const u16* __restrict__ h,
                                                      int* __restrict__ flag,
                                                      int* __restrict__ deg) {
  int i = blockIdx.x * 256 + threadIdx.x;
  if (i < N_NODES) deg[i] = 0;
  if (blockIdx.x == 0) {
    int t = threadIdx.x;
    int bad = 0;
#pragma unroll
    for (int j = 0; j < 4; j++) {
      u32 e = ((u32)h[t * 4 + j] >> 7) & 0xFFu;
      if (e >= 0x8Eu) bad = 1;  // impossible magnitude for N(0,1) bf16 data
    }
    int r = __syncthreads_or(bad);
    if (t == 0) *flag = r ? 1 : 0;
  }
}

struct ConvDesc { const void* s; u16* d; int n; int off; };
struct ConvTab { ConvDesc e[20]; int total; };

// ---------------- fused front-end: deg_count | conv h | conv ef | conv params ----------------
// blocks [0,1875): deg_count; [1875,5625): h conv x4; [5625,8438): ef conv x4; rest: params.
__global__ __launch_bounds__(256) void conv_all(
    const int* __restrict__ dstE, int* __restrict__ deg,
    const void* __restrict__ hsrc, u16* __restrict__ c_h,
    const void* __restrict__ efsrc, u16* __restrict__ c_ef,
    ConvTab tab, const int* __restrict__ flag) {
  int b = blockIdx.x;
  const int t = threadIdx.x;
  if (b < 1875) {
    int e = b * 256 + t;
    if (e < N_EDGES) atomicAdd(&deg[dstE[e]], 1);
    return;
  }
  b -= 1875;
  const int f = *flag;
  if (b < 3750) {  // h: 960000 uint2-groups
    int i = b * 256 + t;
    if (f) {
      float4 v = ((const float4*)hsrc)[i];
      uint2 o;
      o.x = (u32)f2b(v.x) | ((u32)f2b(v.y) << 16);
      o.y = (u32)f2b(v.z) | ((u32)f2b(v.w) << 16);
      ((uint2*)c_h)[i] = o;
    } else {
      ((uint2*)c_h)[i] = ((const uint2*)hsrc)[i];
    }
    return;
  }
  b -= 3750;
  if (b < 2813) {  // ef: 720000 4-elem groups
    int i = b * 256 + t;
    if (i < 720000) {
      if (f) {
        float4 v = ((const float4*)efsrc)[i];
        uint2 o;
        o.x = (u32)f2b(v.x) | ((u32)f2b(v.y) << 16);
        o.y = (u32)f2b(v.z) | ((u32)f2b(v.w) << 16);
        ((uint2*)c_ef)[i] = o;
      } else {
        ((uint2*)c_ef)[i] = ((const uint2*)efsrc)[i];
      }
    }
    return;
  }
  b -= 2813;
  int i = b * 256 + t;
  if (i >= tab.total) return;
#pragma unroll 1
  for (int a = 0; a < 20; a++) {
    int j = i - tab.e[a].off;
    if (j >= 0 && j < tab.e[a].n) {
      if (f) tab.e[a].d[j] = f2b(((const float*)tab.e[a].s)[j]);
      else tab.e[a].d[j] = ((const u16*)tab.e[a].s)[j];
      return;
    }
  }
}

__global__ __launch_bounds__(1024) void scan_off(const int* __restrict__ deg,
                                                 int* __restrict__ off,
                                                 int* __restrict__ cursor, int n) {
  __shared__ int carry;
  __shared__ int wsum[16];
  int t = threadIdx.x, lane = t & 63, wv = t >> 6;
  if (t == 0) { carry = 0; off[0] = 0; }
  __syncthreads();
  for (int base = 0; base < n; base += 1024) {
    int v = (base + t < n) ? deg[base + t] : 0;
    int x = v;
#pragma unroll
    for (int d = 1; d < 64; d <<= 1) {
      int y = __shfl_up(x, d, 64);
      if (lane >= d) x += y;
    }
    if (lane == 63) wsum[wv] = x;
    __syncthreads();
    int wadd = 0;
    for (int w = 0; w < wv; w++) wadd += wsum[w];
    int incl = x + wadd + carry;
    if (base + t < n) { off[base + t + 1] = incl; cursor[base + t] = incl - v; }
    __syncthreads();
    if (t == 1023) carry = incl;
    __syncthreads();
  }
}

__global__ __launch_bounds__(256) void fill_csr(const int* __restrict__ src,
                                                const int* __restrict__ dst,
                                                int* __restrict__ cursor,
                                                int* __restrict__ esrc, int nE) {
  int e = blockIdx.x * 256 + threadIdx.x;
  if (e >= nE) return;
  int p = atomicAdd(&cursor[dst[e]], 1);
  esrc[p] = src[e];
}

// ---------------- CSR max-aggregate (unsigned max == float max for bf16 >= 0) ----------------
// 4 nodes per wave; 16 lanes x uint4 per row (128 cols).
__global__ __launch_bounds__(256) void agg128(const u16* __restrict__ m,
                                              const int* __restrict__ esrc,
                                              const int* __restrict__ off,
                                              u16* __restrict__ out) {
  int wv = threadIdx.x >> 6, lane = threadIdx.x & 63;
  int qd = lane >> 4, l = lane & 15;
  int n = blockIdx.x * 16 + wv * 4 + qd;
  if (n >= N_NODES) return;
  int i = off[n], s1 = off[n + 1];
  u32 a0 = 0, a1 = 0, a2 = 0, a3 = 0, a4 = 0, a5 = 0, a6 = 0, a7 = 0;
  for (; i + 1 < s1; i += 2) {
    int e0 = esrc[i], e1 = esrc[i + 1];
    uint4 r0 = *(const uint4*)(m + (size_t)e0 * 128 + l * 8);
    uint4 r1 = *(const uint4*)(m + (size_t)e1 * 128 + l * 8);
    a0 = max(a0, r0.x & 0xffffu); a1 = max(a1, r0.x >> 16);
    a2 = max(a2, r0.y & 0xffffu); a3 = max(a3, r0.y >> 16);
    a4 = max(a4, r0.z & 0xffffu); a5 = max(a5, r0.z >> 16);
    a6 = max(a6, r0.w & 0xffffu); a7 = max(a7, r0.w >> 16);
    a0 = max(a0, r1.x & 0xffffu); a1 = max(a1, r1.x >> 16);
    a2 = max(a2, r1.y & 0xffffu); a3 = max(a3, r1.y >> 16);
    a4 = max(a4, r1.z & 0xffffu); a5 = max(a5, r1.z >> 16);
    a6 = max(a6, r1.w & 0xffffu); a7 = max(a7, r1.w >> 16);
  }
  if (i < s1) {
    uint4 r0 = *(const uint4*)(m + (size_t)esrc[i] * 128 + l * 8);
    a0 = max(a0, r0.x & 0xffffu); a1 = max(a1, r0.x >> 16);
    a2 = max(a2, r0.y & 0xffffu); a3 = max(a3, r0.y >> 16);
    a4 = max(a4, r0.z & 0xffffu); a5 = max(a5, r0.z >> 16);
    a6 = max(a6, r0.w & 0xffffu); a7 = max(a7, r0.w >> 16);
  }
  uint4 w;
  w.x = a0 | (a1 << 16); w.y = a2 | (a3 << 16);
  w.z = a4 | (a5 << 16); w.w = a6 | (a7 << 16);
  *(uint4*)(out + (size_t)n * 128 + l * 8) = w;
}

// 2 nodes per wave; 32 lanes x uint4 per row (256 cols).
__global__ __launch_bounds__(256) void agg256(const u16* __restrict__ m,
                                              const int* __restrict__ esrc,
                                              const int* __restrict__ off,
                                              u16* __restrict__ out) {
  int wv = threadIdx.x >> 6, lane = threadIdx.x & 63;
  int half = lane >> 5, l = lane & 31;
  int n = blockIdx.x * 8 + wv * 2 + half;
  if (n >= N_NODES) return;
  int i = off[n], s1 = off[n + 1];
  u32 a0 = 0, a1 = 0, a2 = 0, a3 = 0, a4 = 0, a5 = 0, a6 = 0, a7 = 0;
  for (; i + 1 < s1; i += 2) {
    int e0 = esrc[i], e1 = esrc[i + 1];
    uint4 r0 = *(const uint4*)(m + (size_t)e0 * 256 + l * 8);
    uint4 r1 = *(const uint4*)(m + (size_t)e1 * 256 + l * 8);
    a0 = max(a0, r0.x & 0xffffu); a1 = max(a1, r0.x >> 16);
    a2 = max(a2, r0.y & 0xffffu); a3 = max(a3, r0.y >> 16);
    a4 = max(a4, r0.z & 0xffffu); a5 = max(a5, r0.z >> 16);
    a6 = max(a6, r0.w & 0xffffu); a7 = max(a7, r0.w >> 16);
    a0 = max(a0, r1.x & 0xffffu); a1 = max(a1, r1.x >> 16);
    a2 = max(a2, r1.y & 0xffffu); a3 = max(a3, r1.y >> 16);
    a4 = max(a4, r1.z & 0xffffu); a5 = max(a5, r1.z >> 16);
    a6 = max(a6, r1.w & 0xffffu); a7 = max(a7, r1.w >> 16);
  }
  if (i < s1) {
    uint4 r0 = *(const uint4*)(m + (size_t)esrc[i] * 256 + l * 8);
    a0 = max(a0, r0.x & 0xffffu); a1 = max(a1, r0.x >> 16);
    a2 = max(a2, r0.y & 0xffffu); a3 = max(a3, r0.y >> 16);
    a4 = max(a4, r0.z & 0xffffu); a5 = max(a5, r0.z >> 16);
    a6 = max(a6, r0.w & 0xffffu); a7 = max(a7, r0.w >> 16);
  }
  uint4 w;
  w.x = a0 | (a1 << 16); w.y = a2 | (a3 << 16);
  w.z = a4 | (a5 << 16); w.w = a6 | (a7 << 16);
  *(uint4*)(out + (size_t)n * 256 + l * 8) = w;
}

// ---------------- fused weight prep: all transposes + UV build + b512 + wefsum ----------------
__global__ __launch_bounds__(256) void prep_weights(
    const u16* __restrict__ encWp, const u16* __restrict__ encWs, const u16* __restrict__ encWn,
    const u16* __restrict__ decWp, const u16* __restrict__ decWs, const u16* __restrict__ decWn,
    const u16* __restrict__ epW1, const u16* __restrict__ epb1,
    u16* __restrict__ wt_encpool, u16* __restrict__ wt_enc,
    u16* __restrict__ wt_decpool, u16* __restrict__ wt_dec,
    u16* __restrict__ wt_UV, u16* __restrict__ b512, float* __restrict__ swsum) {
  int b = blockIdx.x;
  const int t = threadIdx.x;
  if (b < 64) {
    int idx = b * 256 + t; int k = idx >> 7, n = idx & 127;
    wt_encpool[n * 128 + k] = encWp[k * 128 + n]; return;
  }
  b -= 64;
  if (b < 128) {
    int idx = b * 256 + t; int k = idx >> 8, n = idx & 255;
    wt_enc[n * 256 + k] = encWs[k * 256 + n]; return;
  }
  b -= 128;
  if (b < 128) {
    int idx = b * 256 + t; int k = idx >> 8, n = idx & 255;
    wt_enc[n * 256 + 128 + k] = encWn[k * 256 + n]; return;
  }
  b -= 128;
  if (b < 256) {
    int idx = b * 256 + t; int k = idx >> 8, n = idx & 255;
    wt_decpool[n * 256 + k] = decWp[k * 256 + n]; return;
  }
  b -= 256;
  if (b < 128) {
    int idx = b * 256 + t; int k = idx >> 7, n = idx & 127;
    wt_dec[n * 512 + k] = decWs[k * 128 + n]; return;
  }
  b -= 128;
  if (b < 128) {
    int idx = b * 256 + t; int k = idx >> 7, n = idx & 127;
    wt_dec[n * 512 + 256 + k] = decWn[k * 128 + n]; return;
  }
  b -= 128;
  if (b < 512) {
    int n = b, n2 = n & 255, base = (n >= 256) ? 267 : 0;
    for (int kp = t; kp < 288; kp += 256) {
      u16 v = (kp < 261) ? epW1[(size_t)(base + kp) * 256 + n2] : (u16)0;
      wt_UV[(size_t)n * 288 + kp] = v;
    }
    return;
  }
  b -= 512;
  if (b < 2) {
    int i = b * 256 + t;
    b512[i] = (i < 256) ? epb1[i] : (u16)0; return;
  }
  int k = t >> 5, l32 = t & 31;
  if (k < 6) {
    uint4 v = *(const uint4*)(epW1 + (size_t)(261 + k) * 256 + l32 * 8);
    float s = b2f_lo(v.x) + b2f_hi(v.x) + b2f_lo(v.y) + b2f_hi(v.y) +
              b2f_lo(v.z) + b2f_hi(v.z) + b2f_lo(v.w) + b2f_hi(v.w);
#pragma unroll
    for (int m = 1; m < 32; m <<= 1) s += __shfl_xor(s, m, 64);
    if (l32 == 0) swsum[k] = s;
  }
}

// ---------------- generic MFMA GEMM: C = act(concat(A0,A1) @ Bt^T + bias) ----------------
__global__ __launch_bounds__(256) void gemm_mfma(
    const u16* __restrict__ A0, const u16* __restrict__ A1, int K0, int K1,
    const u16* __restrict__ Bt, const u16* __restrict__ bias, int do_relu,
    u16* __restrict__ C, float* __restrict__ Cf, const int* __restrict__ flag,
    int M, int Nld) {
  __shared__ __align__(16) u16 As[128 * 40];
  __shared__ __align__(16) u16 Bs[128 * 40];
  const int t = threadIdx.x;
  const int lane = t & 63, wv = t >> 6;
  const int wm = wv & 1, wn = wv >> 1;
  const int r = lane & 15, q = lane >> 4;
  const int bm = blockIdx.x, bn = blockIdx.y;
  const int Ktot = K0 + K1;
  const bool usef = (Cf != nullptr) && (*flag != 0);

  f32x4 acc[4][4];
#pragma unroll
  for (int i = 0; i < 4; i++)
#pragma unroll
    for (int j = 0; j < 4; j++) acc[i][j] = (f32x4){0.f, 0.f, 0.f, 0.f};

  for (int kc = 0; kc < Ktot; kc += 32) {
#pragma unroll
    for (int h = 0; h < 2; h++) {
      int idx = t + h * 256;          // 0..511
      int rr = idx >> 2, qq = idx & 3;
      int rowg = bm * 128 + rr;
      uint4 av = make_uint4(0, 0, 0, 0);
      if (rowg < M) {
        const u16* p = (kc < K0) ? (A0 + (size_t)rowg * K0 + kc)
                                 : (A1 + (size_t)rowg * K1 + (kc - K0));
        av = *(const uint4*)(p + qq * 8);
      }
      *(uint4*)&As[rr * 40 + qq * 8] = av;
      int ng = bn * 128 + rr;
      uint4 bv = *(const uint4*)(Bt + (size_t)ng * Ktot + kc + qq * 8);
      *(uint4*)&Bs[rr * 40 + qq * 8] = bv;
    }
    __syncthreads();
    bf16x8 af[4], bfm[4];
#pragma unroll
    for (int mi = 0; mi < 4; mi++)
      af[mi] = *(const bf16x8*)&As[(wm * 64 + mi * 16 + r) * 40 + q * 8];
#pragma unroll
    for (int ni = 0; ni < 4; ni++)
      bfm[ni] = *(const bf16x8*)&Bs[(wn * 64 + ni * 16 + r) * 40 + q * 8];
#pragma unroll
    for (int mi = 0; mi < 4; mi++)
#pragma unroll
      for (int ni = 0; ni < 4; ni++)
        acc[mi][ni] = __builtin_amdgcn_mfma_f32_16x16x32_bf16(af[mi], bfm[ni], acc[mi][ni], 0, 0, 0);
    __syncthreads();
  }

  float bv[4];
#pragma unroll
  for (int ni = 0; ni < 4; ni++)
    bv[ni] = bias ? b2f(bias[bn * 128 + wn * 64 + ni * 16 + r]) : 0.f;
#pragma unroll
  for (int mi = 0; mi < 4; mi++) {
#pragma unroll
    for (int i = 0; i < 4; i++) {
      int rowg = bm * 128 + wm * 64 + mi * 16 + q * 4 + i;
      if (rowg >= M) continue;
#pragma unroll
      for (int ni = 0; ni < 4; ni++) {
        int colg = bn * 128 + wn * 64 + ni * 16 + r;
        float v = acc[mi][ni][i] + bv[ni];
        if (do_relu) v = v > 0.f ? v : 0.f;
        if (usef) Cf[(size_t)rowg * Nld + colg] = v;
        else C[(size_t)rowg * Nld + colg] = f2b(v);
      }
    }
  }
}

// ---------------- node head: node_pred = LN(h1@W + b), smb32 = [softmax | 0-pad] ----------------
__global__ __launch_bounds__(256) void node_head(
    const u16* __restrict__ h1, const u16* __restrict__ W, const u16* __restrict__ b,
    const u16* __restrict__ g, const u16* __restrict__ beta,
    u16* __restrict__ outN, float* __restrict__ outNf, const int* __restrict__ flag,
    u16* __restrict__ smOut) {
  __shared__ float Wl[256 * 5];
  __shared__ float bl[5], gl[5], betal[5];
  int t = threadIdx.x;
#pragma unroll
  for (int c = 0; c < 5; c++) Wl[t * 5 + c] = b2f(W[t * 5 + c]);
  if (t < 5) { bl[t] = b2f(b[t]); gl[t] = b2f(g[t]); betal[t] = b2f(beta[t]); }
  __syncthreads();
  int n = blockIdx.x * 256 + t;
  if (n >= N_NODES) return;
  const bool usef = (*flag != 0);
  float acc[5] = {0.f, 0.f, 0.f, 0.f, 0.f};
  const u16* hp = h1 + (size_t)n * 256;
  for (int k8 = 0; k8 < 32; k8++) {
    uint4 v = *(const uint4*)(hp + k8 * 8);
    u32 wds[4] = {v.x, v.y, v.z, v.w};
#pragma unroll
    for (int h = 0; h < 4; h++) {
      float x0 = b2f_lo(wds[h]), x1 = b2f_hi(wds[h]);
      int k = k8 * 8 + h * 2;
#pragma unroll
      for (int c = 0; c < 5; c++)
        acc[c] += x0 * Wl[k * 5 + c] + x1 * Wl[(k + 1) * 5 + c];
    }
  }
  float x[5], mu = 0.f;
#pragma unroll
  for (int c = 0; c < 5; c++) { x[c] = acc[c] + bl[c]; mu += x[c]; }
  mu *= 0.2f;
  float var = 0.f;
#pragma unroll
  for (int c = 0; c < 5; c++) { float d = x[c] - mu; var += d * d; }
  var *= 0.2f;
  float rstd = rsqrtf(fmaxf(var, 0.f) + 1e-5f);
  float v5[5], mx = -1e30f;
#pragma unroll
  for (int c = 0; c < 5; c++) {
    v5[c] = gl[c] * (x[c] - mu) * rstd + betal[c];
    if (usef) outNf[(size_t)n * 5 + c] = v5[c];
    else outN[(size_t)n * 5 + c] = f2b(v5[c]);
    mx = fmaxf(mx, v5[c]);
  }
  float s = 0.f, ex[5];
#pragma unroll
  for (int c = 0; c < 5; c++) { ex[c] = __expf(v5[c] - mx); s += ex[c]; }
  float inv = 1.f / s;
  u16 row[32];
#pragma unroll
  for (int c = 0; c < 5; c++) row[c] = f2b(ex[c] * inv);
#pragma unroll
  for (int c = 5; c < 32; c++) row[c] = 0;
#pragma unroll
  for (int c = 0; c < 4; c++)
    *(uint4*)(smOut + (size_t)n * 32 + c * 8) = *(const uint4*)&row[c * 8];
}

// ---------------- row sums of UV ----------------
__global__ __launch_bounds__(256) void rowsum_uv(const u16* __restrict__ UV,
                                                 float2* __restrict__ Srow) {
  int wv = threadIdx.x >> 6, lane = threadIdx.x & 63;
  int n = blockIdx.x * 4 + wv;
  if (n >= N_NODES) return;
  uint4 v = *(const uint4*)(UV + (size_t)n * 512 + lane * 8);
  float s = b2f_lo(v.x) + b2f_hi(v.x) + b2f_lo(v.y) + b2f_hi(v.y) +
            b2f_lo(v.z) + b2f_hi(v.z) + b2f_lo(v.w) + b2f_hi(v.w);
#pragma unroll
  for (int m = 1; m < 32; m <<= 1) s += __shfl_xor(s, m, 64);
  if (lane == 0) Srow[n].x = s;    // U half (lanes 0-31)
  if (lane == 32) Srow[n].y = s;   // V half (lanes 32-63)
}

// ---------------- edge mean + record pack: per PAIR of edges, 48B record ----------------
// record dwords: [0]=src0 [1]=dst0 [2]=src1 [3]=dst1 | [4]=m0 [5]=m1 [6..8]=ef0 | [9..11]=ef1
__global__ __launch_bounds__(256) void edge_mean(
    const int* __restrict__ src, const int* __restrict__ dst,
    const u16* __restrict__ ef, const float2* __restrict__ Srow,
    const float* __restrict__ swsum, uint4* __restrict__ recs) {
  int p = blockIdx.x * 256 + threadIdx.x;
  if (p >= 240000) return;
  int e = p * 2;
  int s0 = src[e], s1 = src[e + 1];
  int d0 = dst[e], d1 = dst[e + 1];
  const u32* efp = (const u32*)(ef + (size_t)e * 6);
  u32 f0 = efp[0], f1 = efp[1], f2 = efp[2], f3 = efp[3], f4 = efp[4], f5 = efp[5];
  float xa[6] = {b2f_lo(f0), b2f_hi(f0), b2f_lo(f1), b2f_hi(f1), b2f_lo(f2), b2f_hi(f2)};
  float xb[6] = {b2f_lo(f3), b2f_hi(f3), b2f_lo(f4), b2f_hi(f4), b2f_lo(f5), b2f_hi(f5)};
  float sw[6];
#pragma unroll
  for (int k = 0; k < 6; k++) sw[k] = swsum[k];
  // EXACT same op order as the original in-loop mean computation.
  float m0 = Srow[s0].x + Srow[d0].y;
  float m1 = Srow[s1].x + Srow[d1].y;
#pragma unroll
  for (int k = 0; k < 6; k++) { m0 += xa[k] * sw[k]; m1 += xb[k] * sw[k]; }
  m0 *= (1.f / 256.f);
  m1 *= (1.f / 256.f);
  uint4 ra, rb, rc;
  ra.x = (u32)s0; ra.y = (u32)d0; ra.z = (u32)s1; ra.w = (u32)d1;
  rb.x = __float_as_uint(m0); rb.y = __float_as_uint(m1); rb.z = f0; rb.w = f1;
  rc.x = f2; rc.y = f3; rc.z = f4; rc.w = f5;
  recs[(size_t)p * 3 + 0] = ra;
  recs[(size_t)p * 3 + 1] = rb;
  recs[(size_t)p * 3 + 2] = rc;
}

// ---------------- edge pointwise v4: scalarized uniforms + packed-f32 column math ----------------
// All wave-uniform values (src/dst/m/ef) come from 48B pair-records via readfirstlane-forced
// s_load; UV gathers use SGPR base + constant per-lane voffset; per-column math uses f32x2
// so the compiler can emit v_pk_{add,mul,fma,max}_f32. Reduction chains keep the original
// scalar association (bitwise-stable vs v3).
__global__ __launch_bounds__(256) void edge_pt(
    const u16* __restrict__ UV, const uint4* __restrict__ recs,
    const u16* __restrict__ w1raw,
    const u16* __restrict__ g, const u16* __restrict__ beta,
    const u16* __restrict__ w2, const u16* __restrict__ b2,
    u16* __restrict__ outE, float* __restrict__ outEf, const int* __restrict__ flag) {
  const int t = threadIdx.x;
  const int lane = t & 63, wv = t >> 6;
  const int c0 = lane * 4;
  const int grp = (lane >> 4) & 3;  // 16-lane group id
  f32x2 wefA[6], wefB[6];           // ef->W1 rows, cols {c0,c0+1} / {c0+2,c0+3}
#pragma unroll
  for (int k = 0; k < 6; k++) {
    u32 wa = *(const u32*)(w1raw + (size_t)(261 + k) * 256 + c0);
    u32 wb = *(const u32*)(w1raw + (size_t)(261 + k) * 256 + c0 + 2);
    wefA[k] = (f32x2){b2f_lo(wa), b2f_hi(wa)};
    wefB[k] = (f32x2){b2f_lo(wb), b2f_hi(wb)};
  }
  f32x2 glA = (f32x2){b2f(g[c0]), b2f(g[c0 + 1])};
  f32x2 glB = (f32x2){b2f(g[c0 + 2]), b2f(g[c0 + 3])};
  f32x2 blA = (f32x2){b2f(beta[c0]), b2f(beta[c0 + 1])};
  f32x2 blB = (f32x2){b2f(beta[c0 + 2]), b2f(beta[c0 + 3])};
  float w20[4], w21[4];
#pragma unroll
  for (int j = 0; j < 4; j++) {
    w20[j] = b2f(w2[(c0 + j) * 2]); w21[j] = b2f(w2[(c0 + j) * 2 + 1]);
  }
  const float b20 = b2f(b2[0]), b21 = b2f(b2[1]);
  const float bsel = (grp & 1) ? b21 : b20;
  const bool usef = (*flag != 0);
  const f32x2 zero2 = (f32x2){0.f, 0.f};

  // pair index base — force uniform so record loads become s_load
  const int pb = __builtin_amdgcn_readfirstlane((blockIdx.x * 4 + wv) * 16);
  const uint4* rp = recs + (size_t)pb * 3;
  uint4 ra = rp[0], rb = rp[1], rc = rp[2];
#pragma unroll 1
  for (int it = 0; it < 16; ++it) {
    const int e = (pb + it) * 2;
    uint4 ca = ra, cb = rb, cc = rc;
    // prefetch next record (tail over-read lands in pad allocation)
    ra = rp[3 * it + 3]; rb = rp[3 * it + 4]; rc = rp[3 * it + 5];
    const int s0 = (int)ca.x, d0 = (int)ca.y, s1 = (int)ca.z, d1 = (int)ca.w;
    const float ma = __uint_as_float(cb.x), mb = __uint_as_float(cb.y);
    float xa[6] = {b2f_lo(cb.z), b2f_hi(cb.z), b2f_lo(cb.w), b2f_hi(cb.w),
                   b2f_lo(cc.x), b2f_hi(cc.x)};
    float xb[6] = {b2f_lo(cc.y), b2f_hi(cc.y), b2f_lo(cc.z), b2f_hi(cc.z),
                   b2f_lo(cc.w), b2f_hi(cc.w)};
    // UV gathers: SGPR base + constant per-lane offset
    uint2 ua = *(const uint2*)(UV + ((size_t)(u32)s0 << 9) + c0);
    uint2 va = *(const uint2*)(UV + ((size_t)(u32)d0 << 9) + 256 + c0);
    uint2 ub = *(const uint2*)(UV + ((size_t)(u32)s1 << 9) + c0);
    uint2 vb = *(const uint2*)(UV + ((size_t)(u32)d1 << 9) + 256 + c0);

    f32x2 yaA = (f32x2){b2f_lo(ua.x), b2f_hi(ua.x)} + (f32x2){b2f_lo(va.x), b2f_hi(va.x)};
    f32x2 yaB = (f32x2){b2f_lo(ua.y), b2f_hi(ua.y)} + (f32x2){b2f_lo(va.y), b2f_hi(va.y)};
    f32x2 ybA = (f32x2){b2f_lo(ub.x), b2f_hi(ub.x)} + (f32x2){b2f_lo(vb.x), b2f_hi(vb.x)};
    f32x2 ybB = (f32x2){b2f_lo(ub.y), b2f_hi(ub.y)} + (f32x2){b2f_lo(vb.y), b2f_hi(vb.y)};
#pragma unroll
    for (int k = 0; k < 6; k++) {
      yaA += xa[k] * wefA[k];
      yaB += xa[k] * wefB[k];
      ybA += xb[k] * wefA[k];
      ybB += xb[k] * wefB[k];
    }
    // sum of squares — original scalar association
    float pqa = yaA.x * yaA.x;
    pqa += yaA.y * yaA.y; pqa += yaB.x * yaB.x; pqa += yaB.y * yaB.y;
    float pqb = ybA.x * ybA.x;
    pqb += ybA.y * ybA.y; pqb += ybB.x * ybB.x; pqb += ybB.y * ybB.y;
    pqa += __shfl_xor(pqa, 32, 64);
    pqb += __shfl_xor(pqb, 32, 64);
    float z = (lane < 32) ? pqa : pqb;
#pragma unroll
    for (int m = 16; m >= 1; m >>= 1) z += __shfl_xor(z, m, 64);
    float zz = __shfl_xor(z, 32, 64);
    float pqa_t = (lane < 32) ? z : zz;
    float pqb_t = (lane < 32) ? zz : z;
    float rsa = rsqrtf(fmaxf(pqa_t * (1.f / 256.f) - ma * ma, 0.f) + 1e-5f);
    float rsb = rsqrtf(fmaxf(pqb_t * (1.f / 256.f) - mb * mb, 0.f) + 1e-5f);
    // LN + relu, packed (elementwise ops identical to scalar version)
    f32x2 nAa = __builtin_elementwise_max((yaA - ma) * rsa * glA + blA, zero2);
    f32x2 nAb = __builtin_elementwise_max((yaB - ma) * rsa * glB + blB, zero2);
    f32x2 nBa = __builtin_elementwise_max((ybA - mb) * rsb * glA + blA, zero2);
    f32x2 nBb = __builtin_elementwise_max((ybB - mb) * rsb * glB + blB, zero2);
    // final 2-wide matvec — original scalar association
    float p0a = nAa.x * w20[0], p1a = nAa.x * w21[0];
    p0a += nAa.y * w20[1]; p1a += nAa.y * w21[1];
    p0a += nAb.x * w20[2]; p1a += nAb.x * w21[2];
    p0a += nAb.y * w20[3]; p1a += nAb.y * w21[3];
    float p0b = nBa.x * w20[0], p1b = nBa.x * w21[0];
    p0b += nBa.y * w20[1]; p1b += nBa.y * w21[1];
    p0b += nBb.x * w20[2]; p1b += nBb.x * w21[2];
    p0b += nBb.y * w20[3]; p1b += nBb.y * w21[3];
    p0a += __shfl_xor(p0a, 32, 64); p1a += __shfl_xor(p1a, 32, 64);
    p0b += __shfl_xor(p0b, 32, 64); p1b += __shfl_xor(p1b, 32, 64);
    p0a += __shfl_xor(p0a, 16, 64); p1a += __shfl_xor(p1a, 16, 64);
    p0b += __shfl_xor(p0b, 16, 64); p1b += __shfl_xor(p1b, 16, 64);
    float w = (grp & 2) ? ((grp & 1) ? p1b : p0b) : ((grp & 1) ? p1a : p0a);
#pragma unroll
    for (int m = 8; m >= 1; m >>= 1) w += __shfl_xor(w, m, 64);
    if ((lane & 15) == 0) {
      float val = w + bsel;
      size_t oi = (size_t)e * 2 + grp;
      if (usef) outEf[oi] = val;
      else outE[oi] = f2b(val);
    }
  }
}

extern "C" void kernel_launch(void* const* d_in, const int* in_sizes, int n_in,
                              void* d_out, int out_size, void* d_ws, size_t ws_size,
                              hipStream_t stream) {
  char* wp = (char*)d_ws;
  auto alloc = [&](size_t bytes) -> char* {
    char* p = wp; wp += (bytes + 255) & ~(size_t)255; return p;
  };
  int* flag       = (int*)alloc(256);
  u16* c_h        = (u16*)alloc((size_t)N_NODES * 128 * 2);
  u16* c_ef       = (u16*)alloc((size_t)N_EDGES * 6 * 2);
  static const int pidx[20] = {4,5,6,7,8, 9,10,11,12, 13,14,15,16,17,18, 19,20,21,22,23};
  static const int pn[20]   = {16384,128,32768,256,32768, 1280,5,5,5,
                               135168,256,256,256,512,2, 65536,256,32768,128,32768};
  u16* cp[20];
  for (int a = 0; a < 20; a++) cp[a] = (u16*)alloc((size_t)pn[a] * 2);

  u16* wt_encpool = (u16*)alloc(128 * 128 * 2);
  u16* wt_enc     = (u16*)alloc(256 * 256 * 2);
  u16* wt_decpool = (u16*)alloc(256 * 256 * 2);
  u16* wt_dec     = (u16*)alloc(128 * 512 * 2);
  u16* wt_UV      = (u16*)alloc(512 * 288 * 2);
  u16* b512       = (u16*)alloc(512 * 2);
  float2* Srow    = (float2*)alloc((size_t)N_NODES * 8);
  float* swsum_b  = (float*)alloc(64);
  u16* m_buf      = (u16*)alloc((size_t)N_NODES * 256 * 2);
  u16* aggb       = (u16*)alloc((size_t)N_NODES * 256 * 2);
  u16* UVbuf      = m_buf;  // m_buf+aggb contiguous => [N][512] during edge phase
  u16* h1b        = (u16*)alloc((size_t)N_NODES * 256 * 2);
  u16* smb32      = (u16*)alloc((size_t)N_NODES * 32 * 2);
  int* deg        = (int*)alloc((size_t)N_NODES * 4);
  int* off        = (int*)alloc((size_t)(N_NODES + 1) * 4);
  int* cursor     = (int*)alloc((size_t)N_NODES * 4);
  int* esrc       = (int*)alloc((size_t)N_EDGES * 4);
  uint4* recs     = (uint4*)alloc(((size_t)240000 * 3 + 8) * 16);  // 48B/pair + prefetch pad

  const int* src = (const int*)d_in[2];
  const int* dst = (const int*)d_in[3];

  u16* outN = (u16*)d_out;
  u16* outE = outN + (size_t)N_NODES * 5;
  u16* outH = outN + 1110000;
  float* outNf = (float*)d_out;
  float* outEf = outNf + (size_t)N_NODES * 5;
  float* outHf = outNf + 1110000;

  // --- init (deg zero + dtype sniff) ---
  init_sniff_deg<<<118, 256, 0, stream>>>((const u16*)d_in[0], flag, deg);
  // --- fused front-end: deg_count + all conversions ---
  ConvTab tab;
  int off_a = 0;
  for (int a = 0; a < 20; a++) {
    tab.e[a].s = d_in[pidx[a]]; tab.e[a].d = cp[a]; tab.e[a].n = pn[a]; tab.e[a].off = off_a;
    off_a += pn[a];
  }
  tab.total = off_a;
  int conv_blocks = 1875 + 3750 + 2813 + (off_a + 255) / 256;
  conv_all<<<conv_blocks, 256, 0, stream>>>(dst, deg, d_in[0], c_h, d_in[1], c_ef, tab, flag);

  const u16 *enc_Wpool = cp[0], *enc_bpool = cp[1], *enc_Wself = cp[2], *enc_bself = cp[3],
            *enc_Wneigh = cp[4], *np_W = cp[5], *np_b = cp[6], *np_g = cp[7], *np_beta = cp[8],
            *ep_W1 = cp[9], *ep_b1 = cp[10], *ep_g = cp[11], *ep_beta = cp[12],
            *ep_W2 = cp[13], *ep_b2 = cp[14], *dec_Wpool = cp[15], *dec_bpool = cp[16],
            *dec_Wself = cp[17], *dec_bself = cp[18], *dec_Wneigh = cp[19];

  // --- CSR build ---
  scan_off<<<1, 1024, 0, stream>>>(deg, off, cursor, N_NODES);
  fill_csr<<<1875, 256, 0, stream>>>(src, dst, cursor, esrc, N_EDGES);

  // --- fused weight prep ---
  prep_weights<<<1347, 256, 0, stream>>>(enc_Wpool, enc_Wself, enc_Wneigh,
                                         dec_Wpool, dec_Wself, dec_Wneigh,
                                         ep_W1, ep_b1,
                                         wt_encpool, wt_enc, wt_decpool, wt_dec,
                                         wt_UV, b512, swsum_b);

  // --- encoder ---
  gemm_mfma<<<dim3(235, 1), 256, 0, stream>>>(c_h, nullptr, 128, 0, wt_encpool,
                                              enc_bpool, 1, m_buf, nullptr, flag, N_NODES, 128);
  agg128<<<1875, 256, 0, stream>>>(m_buf, esrc, off, aggb);
  gemm_mfma<<<dim3(235, 2), 256, 0, stream>>>(c_h, aggb, 128, 128, wt_enc,
                                              enc_bself, 1, h1b, nullptr, flag, N_NODES, 256);
  // --- node head ---
  node_head<<<118, 256, 0, stream>>>(h1b, np_W, np_b, np_g, np_beta, outN, outNf, flag, smb32);
  // --- edge head: UV GEMM -> row sums -> edge means -> pointwise ---
  gemm_mfma<<<dim3(235, 4), 256, 0, stream>>>(h1b, smb32, 256, 32, wt_UV,
                                              b512, 0, UVbuf, nullptr, flag, N_NODES, 512);
  rowsum_uv<<<7500, 256, 0, stream>>>(UVbuf, Srow);
  edge_mean<<<938, 256, 0, stream>>>(src, dst, c_ef, Srow, swsum_b, recs);
  edge_pt<<<3750, 256, 0, stream>>>(UVbuf, recs, ep_W1, ep_g, ep_beta, ep_W2, ep_b2,
                                    outE, outEf, flag);
  // --- decoder ---
  gemm_mfma<<<dim3(235, 2), 256, 0, stream>>>(h1b, nullptr, 256, 0, wt_decpool,
                                              dec_bpool, 1, m_buf, nullptr, flag, N_NODES, 256);
  agg256<<<3750, 256, 0, stream>>>(m_buf, esrc, off, aggb);
  gemm_mfma<<<dim3(235, 1), 256, 0, stream>>>(h1b, aggb, 256, 256, wt_dec,
                                              dec_bself, 1, outH, outHf, flag, N_NODES, 128);
}